// Round 1
// baseline (1869.807 us; speedup 1.0000x reference)
//
#include <hip/hip_runtime.h>
#include <math.h>

#define HW 21025        // 145*145
#define Hdim 145
#define Wdim 145
#define NBANDS 200
#define CONVH 147
#define QC 64
#define NCH 329         // ceil(21025/64)

// ---------------- workspace layout (float offsets) ----------------
#define OFF_XN   ((size_t)0)          // 4,205,000   (later: pr, cls0)
#define OFF_XT   ((size_t)4205000)    // 4,205,000   (later: p, cls1)
#define OFF_F1   ((size_t)8410000)    // 5,382,400   (later: y  L x 256)
#define OFF_F    ((size_t)13792400)   // 2,691,200   (later: m_out)
#define OFF_C1   ((size_t)16483600)   // 691,488     (later: dt [84100] + chunkT [1316])
#define OFF_C2   ((size_t)17175088)   // 1,382,976   (later: cls2 L x 64)
#define OFF_CF   ((size_t)18558064)   // 1,345,600
#define OFF_ZX   ((size_t)19903664)   // 16,231,300
#define OFF_XBC  ((size_t)36134964)   // 10,764,800
#define OFF_S    ((size_t)46899764)   // 10,780,672
// total 57,680,436 floats ~= 220 MB

__device__ __forceinline__ float gelu_f(float x){
    return 0.5f * x * (1.0f + erff(x * 0.70710678118654752440f));
}
__device__ __forceinline__ float silu_f(float x){
    return x / (1.0f + expf(-x));
}

// ---------------- LayerNorm (+ optional GELU) ----------------
template<int ACT>
__global__ void ln_kernel(const float* __restrict__ in, const float* __restrict__ g,
                          const float* __restrict__ b, float* __restrict__ out, int D){
    int row = blockIdx.x, tid = threadIdx.x;
    const float* r = in + (size_t)row * D;
    float s = 0.f, s2 = 0.f;
    for (int i = tid; i < D; i += 256){ float v = r[i]; s += v; s2 += v*v; }
    __shared__ float r1[4], r2[4];
    #pragma unroll
    for (int o = 32; o > 0; o >>= 1){ s += __shfl_down(s, o); s2 += __shfl_down(s2, o); }
    if ((tid & 63) == 0){ r1[tid >> 6] = s; r2[tid >> 6] = s2; }
    __syncthreads();
    float S = r1[0] + r1[1] + r1[2] + r1[3];
    float S2 = r2[0] + r2[1] + r2[2] + r2[3];
    float mean = S / (float)D;
    float var = S2 / (float)D - mean * mean;
    float rs = rsqrtf(fmaxf(var, 0.f) + 1e-5f);
    float* o_ = out + (size_t)row * D;
    for (int i = tid; i < D; i += 256){
        float v = (r[i] - mean) * rs * g[i] + b[i];
        if (ACT == 1) v = gelu_f(v);
        o_[i] = v;
    }
}

// ---------------- generic 16x16-tile GEMM: C = act(A@B + bias) ----------------
template<int ACT>
__global__ void gemm16(const float* __restrict__ A, const float* __restrict__ B,
                       const float* __restrict__ bias, float* __restrict__ C,
                       int M, int N, int K){
    __shared__ float As[16][17], Bs[16][17];
    int tx = threadIdx.x, ty = threadIdx.y;
    int row = blockIdx.y * 16 + ty, col = blockIdx.x * 16 + tx;
    float acc = 0.f;
    for (int k0 = 0; k0 < K; k0 += 16){
        As[ty][tx] = (row < M && k0 + tx < K) ? A[(size_t)row * K + k0 + tx] : 0.f;
        Bs[ty][tx] = (col < N && k0 + ty < K) ? B[(size_t)(k0 + ty) * N + col] : 0.f;
        __syncthreads();
        #pragma unroll
        for (int kk = 0; kk < 16; kk++) acc += As[ty][kk] * Bs[kk][tx];
        __syncthreads();
    }
    if (row < M && col < N){
        float v = acc + (bias ? bias[col] : 0.f);
        if (ACT == 1) v = gelu_f(v);
        C[(size_t)row * N + col] = v;
    }
}

// concat-A GEMM: A = [A1(128) | A2(64)], K=192, N=128
__global__ void gemm_cat_kernel(const float* __restrict__ A1, const float* __restrict__ A2,
                                const float* __restrict__ B, const float* __restrict__ bias,
                                float* __restrict__ C){
    __shared__ float As[16][17], Bs[16][17];
    int tx = threadIdx.x, ty = threadIdx.y;
    int row = blockIdx.y * 16 + ty, col = blockIdx.x * 16 + tx;
    float acc = 0.f;
    for (int k0 = 0; k0 < 192; k0 += 16){
        int k = k0 + tx;
        float av = 0.f;
        if (row < HW) av = (k < 128) ? A1[(size_t)row * 128 + k] : A2[(size_t)row * 64 + (k - 128)];
        As[ty][tx] = av;
        Bs[ty][tx] = B[(size_t)(k0 + ty) * 128 + col];
        __syncthreads();
        #pragma unroll
        for (int kk = 0; kk < 16; kk++) acc += As[ty][kk] * Bs[kk][tx];
        __syncthreads();
    }
    if (row < HW) C[(size_t)row * 128 + col] = acc + bias[col];
}

// ---------------- HWC -> CHW transpose ----------------
__global__ void transpose_kernel(const float* __restrict__ xn, float* __restrict__ xt){
    size_t idx = (size_t)blockIdx.x * 256 + threadIdx.x;
    if (idx >= (size_t)HW * NBANDS) return;
    int c = (int)(idx % NBANDS);
    size_t pix = idx / NBANDS;
    xt[(size_t)c * HW + pix] = xn[idx];
}

// ---------------- conv1: 200->32, 3x3, pad 2, out 147x147, GELU ----------------
__global__ void conv1_kernel(const float* __restrict__ xt, const float* __restrict__ w,
                             const float* __restrict__ b, float* __restrict__ out){
    int x = blockIdx.x * 16 + threadIdx.x;
    int y = blockIdx.y * 16 + threadIdx.y;
    int o = blockIdx.z;
    if (x >= CONVH || y >= CONVH) return;
    float acc = b[o];
    for (int i = 0; i < NBANDS; i++){
        const float* xp = xt + (size_t)i * HW;
        const float* wp = w + ((size_t)o * NBANDS + i) * 9;
        #pragma unroll
        for (int ky = 0; ky < 3; ky++){
            int yy = y - 2 + ky;
            if ((unsigned)yy >= (unsigned)Hdim) continue;
            #pragma unroll
            for (int kx = 0; kx < 3; kx++){
                int xx = x - 2 + kx;
                if ((unsigned)xx >= (unsigned)Wdim) continue;
                acc += xp[yy * Wdim + xx] * wp[ky * 3 + kx];
            }
        }
    }
    out[((size_t)o * CONVH + y) * CONVH + x] = gelu_f(acc);
}

// ---------------- conv2: 32->64, 3x3, pad 1, 147x147, GELU ----------------
__global__ void conv2_kernel(const float* __restrict__ c1, const float* __restrict__ w,
                             const float* __restrict__ b, float* __restrict__ out){
    int x = blockIdx.x * 16 + threadIdx.x;
    int y = blockIdx.y * 16 + threadIdx.y;
    int o = blockIdx.z;
    if (x >= CONVH || y >= CONVH) return;
    float acc = b[o];
    for (int i = 0; i < 32; i++){
        const float* xp = c1 + (size_t)i * CONVH * CONVH;
        const float* wp = w + ((size_t)o * 32 + i) * 9;
        #pragma unroll
        for (int ky = 0; ky < 3; ky++){
            int yy = y - 1 + ky;
            if ((unsigned)yy >= (unsigned)CONVH) continue;
            #pragma unroll
            for (int kx = 0; kx < 3; kx++){
                int xx = x - 1 + kx;
                if ((unsigned)xx >= (unsigned)CONVH) continue;
                acc += xp[yy * CONVH + xx] * wp[ky * 3 + kx];
            }
        }
    }
    out[((size_t)o * CONVH + y) * CONVH + x] = gelu_f(acc);
}

// ---------------- adaptive pool (64,147,147)->(145,145,64) as rectangle mean ----
__global__ void pool_kernel(const float* __restrict__ c2, float* __restrict__ cf){
    int idx = blockIdx.x * 256 + threadIdx.x;
    if (idx >= HW * 64) return;
    int o = idx & 63;
    int pix = idx >> 6;
    int xo = pix % Wdim, yo = pix / Wdim;
    int ys = yo * CONVH / Hdim, ye = ((yo + 1) * CONVH + Hdim - 1) / Hdim;
    int xs = xo * CONVH / Wdim, xe = ((xo + 1) * CONVH + Wdim - 1) / Wdim;
    float s = 0.f;
    for (int yy = ys; yy < ye; yy++)
        for (int xx = xs; xx < xe; xx++)
            s += c2[((size_t)o * CONVH + yy) * CONVH + xx];
    cf[(size_t)pix * 64 + o] = s / (float)((ye - ys) * (xe - xs));
}

// ---------------- dt = softplus(raw + bias) ----------------
__global__ void dt_kernel(const float* __restrict__ zx, const float* __restrict__ dt_bias,
                          float* __restrict__ dtb){
    int idx = blockIdx.x * 256 + threadIdx.x;
    if (idx >= HW * 4) return;
    int h = idx & 3, t = idx >> 2;
    float v = zx[(size_t)t * 772 + 768 + h] + dt_bias[h];
    dtb[idx] = (v > 20.f) ? v : log1pf(expf(v));
}

// ---------------- depthwise causal conv1d (width 4) + silu ----------------
__global__ void conv1d_kernel(const float* __restrict__ zx, const float* __restrict__ w,
                              const float* __restrict__ b, float* __restrict__ xbc){
    int c = blockIdx.x * 256 + threadIdx.x;
    int t = blockIdx.y;
    if (c >= 512) return;
    float acc = b[c];
    #pragma unroll
    for (int k = 0; k < 4; k++){
        int tt = t - 3 + k;
        if (tt < 0) continue;
        acc += zx[(size_t)tt * 772 + 256 + c] * w[c * 4 + k];
    }
    xbc[(size_t)t * 512 + c] = silu_f(acc);
}

// ---------------- chunk cumsum of a = dt*A (wave 0 scan) ----------------
__device__ __forceinline__ void chunk_cumsum(const float* __restrict__ dtb, int t0, int Q,
                                             int h, float A, float* cum, float* dth){
    int tid = threadIdx.x;
    if (tid < 64){
        float d = (tid < Q) ? dtb[(size_t)(t0 + tid) * 4 + h] : 0.f;
        dth[tid] = d;
        float a = d * A;
        #pragma unroll
        for (int off = 1; off < 64; off <<= 1){
            float u = __shfl_up(a, off);
            if (tid >= off) a += u;
        }
        cum[tid] = a;
    }
    __syncthreads();
}

// ---------------- SSD phase A: chunk-local end states ----------------
__global__ __launch_bounds__(256) void ssd_phaseA(const float* __restrict__ xbc,
                                                  const float* __restrict__ dtb,
                                                  const float* __restrict__ A_log,
                                                  float* __restrict__ S,
                                                  float* __restrict__ chunkT){
    __shared__ float cum[64], dth[64], w[64];
    __shared__ float Bw[32][128];
    __shared__ float Xs[32][64];
    int bid = blockIdx.x, c = bid >> 2, h = bid & 3;
    int t0 = c * QC, Q = min(QC, HW - t0);
    float A = -expf(A_log[h]);
    chunk_cumsum(dtb, t0, Q, h, A, cum, dth);
    int tid = threadIdx.x;
    float T = cum[Q - 1];
    if (tid == 0) chunkT[bid] = T;
    if (tid < 64) w[tid] = (tid < Q) ? __expf(T - cum[tid]) * dth[tid] : 0.f;
    __syncthreads();
    int n = tid >> 1, ph = tid & 1;
    float acc[32];
    #pragma unroll
    for (int j = 0; j < 32; j++) acc[j] = 0.f;
    for (int s0 = 0; s0 < QC; s0 += 32){
        for (int e = tid; e < 32 * 128; e += 256){
            int ss = e >> 7, nn = e & 127;
            int t = t0 + s0 + ss;
            Bw[ss][nn] = (s0 + ss < Q) ? xbc[(size_t)t * 512 + 256 + nn] * w[s0 + ss] : 0.f;
        }
        for (int e = tid; e < 32 * 64; e += 256){
            int ss = e >> 6, pp = e & 63;
            int t = t0 + s0 + ss;
            Xs[ss][pp] = (s0 + ss < Q) ? xbc[(size_t)t * 512 + h * 64 + pp] : 0.f;
        }
        __syncthreads();
        #pragma unroll 4
        for (int ss = 0; ss < 32; ss++){
            float bv = Bw[ss][n];
            #pragma unroll
            for (int j = 0; j < 32; j++) acc[j] += bv * Xs[ss][ph * 32 + j];
        }
        __syncthreads();
    }
    size_t base = ((size_t)bid * 128 + n) * 64 + ph * 32;
    #pragma unroll
    for (int j = 0; j < 32; j++) S[base + j] = acc[j];
}

// ---------------- SSD phase B: in-place prefix over chunks ----------------
__global__ void ssd_phaseB(float* __restrict__ S, const float* __restrict__ chunkT){
    int idx = blockIdx.x * 256 + threadIdx.x;   // 4*128*64 = 32768
    int h = idx >> 13;
    int inner = idx & 8191;
    float s = 0.f;
    for (int c = 0; c < NCH; c++){
        size_t off = ((size_t)(c * 4 + h)) * 8192 + inner;
        float loc = S[off];
        S[off] = s;                              // state BEFORE chunk c
        s = s * expf(chunkT[c * 4 + h]) + loc;
    }
}

// ---------------- SSD phase C: outputs ----------------
__global__ __launch_bounds__(256) void ssd_phaseC(const float* __restrict__ xbc,
                                                  const float* __restrict__ dtb,
                                                  const float* __restrict__ A_log,
                                                  const float* __restrict__ Dvec,
                                                  const float* __restrict__ S,
                                                  float* __restrict__ y){
    __shared__ float cum[64], dth[64];
    __shared__ float P[64][65];
    __shared__ float ubuf[4096];     // union: {Ct[64][17] | BtT[16][68] | SCt[16][64]}  OR  Xs[64][64]
    float* Ct  = ubuf;               // stride 17
    float* BtT = ubuf + 1088;        // stride 68
    float* SCt = ubuf + 2176;        // stride 64
    int bid = blockIdx.x, c = bid >> 2, h = bid & 3;
    int t0 = c * QC, Q = min(QC, HW - t0);
    float A = -expf(A_log[h]);
    chunk_cumsum(dtb, t0, Q, h, A, cum, dth);
    int tid = threadIdx.x;
    int t = tid >> 2, q = tid & 3;
    float acc[16], acc2[16];
    #pragma unroll
    for (int j = 0; j < 16; j++){ acc[j] = 0.f; acc2[j] = 0.f; }
    for (int n0 = 0; n0 < 128; n0 += 16){
        for (int e = tid; e < 1024; e += 256){
            int tt = e >> 4, nn = e & 15;
            Ct[tt * 17 + nn] = (tt < Q) ? xbc[(size_t)(t0 + tt) * 512 + 384 + n0 + nn] : 0.f;
        }
        for (int e = tid; e < 1024; e += 256){
            int tt = e >> 4, nn = e & 15;
            BtT[nn * 68 + tt] = (tt < Q) ? xbc[(size_t)(t0 + tt) * 512 + 256 + n0 + nn] : 0.f;
        }
        for (int e = tid; e < 1024; e += 256){
            int nn = e >> 6, pp = e & 63;
            SCt[nn * 64 + pp] = S[((size_t)bid * 128 + n0 + nn) * 64 + pp];
        }
        __syncthreads();
        #pragma unroll
        for (int nn = 0; nn < 16; nn++){
            float cv = Ct[t * 17 + nn];
            #pragma unroll
            for (int j = 0; j < 16; j++) acc[j]  += cv * BtT[nn * 68 + q * 16 + j];
            #pragma unroll
            for (int j = 0; j < 16; j++) acc2[j] += cv * SCt[nn * 64 + q * 16 + j];
        }
        __syncthreads();
    }
    float ct = cum[t];
    #pragma unroll
    for (int j = 0; j < 16; j++){
        int s = q * 16 + j;
        float pv = 0.f;
        if (s <= t && s < Q) pv = acc[j] * __expf(ct - cum[s]) * dth[s];
        P[t][s] = pv;
    }
    __syncthreads();
    for (int e = tid; e < 4096; e += 256){
        int ss = e >> 6, pp = e & 63;
        ubuf[e] = (ss < Q) ? xbc[(size_t)(t0 + ss) * 512 + h * 64 + pp] : 0.f;
    }
    __syncthreads();
    float ext = __expf(ct);
    float yacc[16];
    #pragma unroll
    for (int j = 0; j < 16; j++) yacc[j] = ext * acc2[j];
    for (int s = 0; s < 64; s++){
        float pv = P[t][s];
        #pragma unroll
        for (int j = 0; j < 16; j++) yacc[j] += pv * ubuf[s * 64 + q * 16 + j];
    }
    if (t < Q){
        float Dh = Dvec[h];
        size_t yb = (size_t)(t0 + t) * 256 + h * 64 + q * 16;
        #pragma unroll
        for (int j = 0; j < 16; j++) y[yb + j] = yacc[j] + Dh * ubuf[t * 64 + q * 16 + j];
    }
}

// ---------------- gated RMSNorm: y = (y*silu(z)) * rsqrt(mean(.^2)+eps) * nw ----
__global__ void gated_rms_kernel(float* __restrict__ y, const float* __restrict__ zx,
                                 const float* __restrict__ nw){
    int row = blockIdx.x, tid = threadIdx.x;
    float v = y[(size_t)row * 256 + tid];
    float z = zx[(size_t)row * 772 + tid];
    v *= silu_f(z);
    float s = v * v;
    __shared__ float r1[4];
    #pragma unroll
    for (int o = 32; o > 0; o >>= 1) s += __shfl_down(s, o);
    if ((tid & 63) == 0) r1[tid >> 6] = s;
    __syncthreads();
    float S = r1[0] + r1[1] + r1[2] + r1[3];
    float rs = rsqrtf(S / 256.f + 1e-5f);
    y[(size_t)row * 256 + tid] = v * rs * nw[tid];
}

extern "C" void kernel_launch(void* const* d_in, const int* in_sizes, int n_in,
                              void* d_out, int out_size, void* d_ws, size_t ws_size,
                              hipStream_t stream){
    (void)in_sizes; (void)n_in; (void)out_size; (void)ws_size;
    const float* x        = (const float*)d_in[0];
    const float* ln_pre_g = (const float*)d_in[1];
    const float* ln_pre_b = (const float*)d_in[2];
    const float* fe_w1    = (const float*)d_in[3];
    const float* fe_b1    = (const float*)d_in[4];
    const float* fe_w2    = (const float*)d_in[5];
    const float* fe_b2    = (const float*)d_in[6];
    const float* cv_w1    = (const float*)d_in[7];
    const float* cv_b1    = (const float*)d_in[8];
    const float* cv_w2    = (const float*)d_in[9];
    const float* cv_b2    = (const float*)d_in[10];
    const float* mp_w     = (const float*)d_in[11];
    const float* mp_b     = (const float*)d_in[12];
    const float* mp_ln_g  = (const float*)d_in[13];
    const float* mp_ln_b  = (const float*)d_in[14];
    const float* m_in_w   = (const float*)d_in[15];
    const float* m_conv_w = (const float*)d_in[16];
    const float* m_conv_b = (const float*)d_in[17];
    const float* m_dtb    = (const float*)d_in[18];
    const float* m_A_log  = (const float*)d_in[19];
    const float* m_D      = (const float*)d_in[20];
    const float* m_norm_w = (const float*)d_in[21];
    const float* m_out_w  = (const float*)d_in[22];
    const float* cls_ln_g = (const float*)d_in[23];
    const float* cls_ln_b = (const float*)d_in[24];
    const float* cls_w1   = (const float*)d_in[25];
    const float* cls_b1   = (const float*)d_in[26];
    const float* cls_w2   = (const float*)d_in[27];
    const float* cls_b2   = (const float*)d_in[28];
    const float* cls_w3   = (const float*)d_in[29];
    const float* cls_b3   = (const float*)d_in[30];

    float* ws   = (float*)d_ws;
    float* xn   = ws + OFF_XN;
    float* xt   = ws + OFF_XT;
    float* f1   = ws + OFF_F1;
    float* f    = ws + OFF_F;
    float* c1   = ws + OFF_C1;
    float* c2   = ws + OFF_C2;
    float* cf   = ws + OFF_CF;
    float* zx   = ws + OFF_ZX;
    float* xbc  = ws + OFF_XBC;
    float* Sbuf = ws + OFF_S;
    // reuse regions
    float* pr    = ws + OFF_XN;            // L x 128 (xn dead)
    float* p     = ws + OFF_XT;            // L x 128 (xt dead)
    float* dtb   = ws + OFF_C1;            // L x 4   (c1 dead)
    float* chkT  = ws + OFF_C1 + 84100;    // 1316
    float* ybuf  = ws + OFF_F1;            // L x 256 (f1 dead)
    float* mo    = ws + OFF_F;             // L x 128 (f dead)
    float* cls0  = ws + OFF_XN;            // L x 128 (pr dead)
    float* cls1v = ws + OFF_XT;            // L x 128 (p dead)
    float* cls2v = ws + OFF_C2;            // L x 64  (c2 dead)

    dim3 tb(16, 16);
    // 1. pre-LN
    ln_kernel<0><<<HW, 256, 0, stream>>>(x, ln_pre_g, ln_pre_b, xn, NBANDS);
    // 2-3. feature MLP
    gemm16<1><<<dim3(16, 1315), tb, 0, stream>>>(xn, fe_w1, fe_b1, f1, HW, 256, NBANDS);
    gemm16<1><<<dim3(8, 1315),  tb, 0, stream>>>(f1, fe_w2, fe_b2, f, HW, 128, 256);
    // 4. transpose for conv
    transpose_kernel<<<(HW * NBANDS + 255) / 256, 256, 0, stream>>>(xn, xt);
    // 5-6. convs
    conv1_kernel<<<dim3(10, 10, 32), tb, 0, stream>>>(xt, cv_w1, cv_b1, c1);
    conv2_kernel<<<dim3(10, 10, 64), tb, 0, stream>>>(c1, cv_w2, cv_b2, c2);
    // 7. adaptive pool -> (pix, 64)
    pool_kernel<<<(HW * 64 + 255) / 256, 256, 0, stream>>>(c2, cf);
    // 8-9. mid projection + LN + GELU
    gemm_cat_kernel<<<dim3(8, 1315), tb, 0, stream>>>(f, cf, mp_w, mp_b, pr);
    ln_kernel<1><<<HW, 256, 0, stream>>>(pr, mp_ln_g, mp_ln_b, p, 128);
    // 10. mamba in_proj
    gemm16<0><<<dim3(49, 1315), tb, 0, stream>>>(p, m_in_w, (const float*)nullptr, zx, HW, 772, 128);
    // 11. dt softplus
    dt_kernel<<<(HW * 4 + 255) / 256, 256, 0, stream>>>(zx, m_dtb, dtb);
    // 12. depthwise causal conv + silu
    conv1d_kernel<<<dim3(2, HW), 256, 0, stream>>>(zx, m_conv_w, m_conv_b, xbc);
    // 13-15. SSD chunked scan
    ssd_phaseA<<<NCH * 4, 256, 0, stream>>>(xbc, dtb, m_A_log, Sbuf, chkT);
    ssd_phaseB<<<128, 256, 0, stream>>>(Sbuf, chkT);
    ssd_phaseC<<<NCH * 4, 256, 0, stream>>>(xbc, dtb, m_A_log, m_D, Sbuf, ybuf);
    // 16. gated RMSNorm
    gated_rms_kernel<<<HW, 256, 0, stream>>>(ybuf, zx, m_norm_w);
    // 17. out proj
    gemm16<0><<<dim3(8, 1315), tb, 0, stream>>>(ybuf, m_out_w, (const float*)nullptr, mo, HW, 128, 256);
    // 18-21. classifier
    ln_kernel<0><<<HW, 256, 0, stream>>>(mo, cls_ln_g, cls_ln_b, cls0, 128);
    gemm16<1><<<dim3(8, 1315), tb, 0, stream>>>(cls0, cls_w1, cls_b1, cls1v, HW, 128, 128);
    gemm16<1><<<dim3(4, 1315), tb, 0, stream>>>(cls1v, cls_w2, cls_b2, cls2v, HW, 64, 128);
    gemm16<0><<<dim3(2, 1315), tb, 0, stream>>>(cls2v, cls_w3, cls_b3, (float*)d_out, HW, 17, 64);
}

// Round 2
// 920.691 us; speedup vs baseline: 2.0309x; 2.0309x over previous
//
#include <hip/hip_runtime.h>
#include <math.h>

#define HW 21025        // 145*145
#define Hdim 145
#define Wdim 145
#define NBANDS 200
#define CONVH 147
#define CONVHW 21609    // 147*147
#define QC 64
#define NCH 329         // ceil(21025/64)

// ---------------- workspace layout (float offsets) ----------------
#define OFF_XN   ((size_t)0)           // 4,205,000  xn; later pr, cls0
#define OFF_F1   ((size_t)4205000)     // 5,382,400  f1; later y (L x 256)
#define OFF_COMB ((size_t)9587400)     // 4,036,800  comb L x 192; later mo + cls2
#define OFF_P    ((size_t)13624200)    // 2,691,200  p; later cls1
#define OFF_ZX   ((size_t)16315400)    // 16,231,300 zxbcdt L x 772
#define OFF_XBC  ((size_t)32546700)    // 10,764,800 c1h+c2h first, then xbc L x 512
#define OFF_S    ((size_t)43311500)    // 10,780,672 convpart first, then S
#define OFF_DT   ((size_t)54092172)    // 84,100
#define OFF_CT   ((size_t)54176272)    // 1,316
// total ~54.2M floats ~= 217 MB

__device__ __forceinline__ float gelu_f(float x){
    return 0.5f * x * (1.0f + erff(x * 0.70710678118654752440f));
}
__device__ __forceinline__ float silu_f(float x){
    return x / (1.0f + expf(-x));
}

// ---------------- LayerNorm (+ optional GELU) ----------------
template<int ACT>
__global__ void ln_kernel(const float* __restrict__ in, const float* __restrict__ g,
                          const float* __restrict__ b, float* __restrict__ out, int D){
    int row = blockIdx.x, tid = threadIdx.x;
    const float* r = in + (size_t)row * D;
    float s = 0.f, s2 = 0.f;
    for (int i = tid; i < D; i += 256){ float v = r[i]; s += v; s2 += v*v; }
    __shared__ float r1[4], r2[4];
    #pragma unroll
    for (int o = 32; o > 0; o >>= 1){ s += __shfl_down(s, o); s2 += __shfl_down(s2, o); }
    if ((tid & 63) == 0){ r1[tid >> 6] = s; r2[tid >> 6] = s2; }
    __syncthreads();
    float S = r1[0] + r1[1] + r1[2] + r1[3];
    float S2 = r2[0] + r2[1] + r2[2] + r2[3];
    float mean = S / (float)D;
    float var = S2 / (float)D - mean * mean;
    float rs = rsqrtf(fmaxf(var, 0.f) + 1e-5f);
    float* o_ = out + (size_t)row * D;
    for (int i = tid; i < D; i += 256){
        float v = (r[i] - mean) * rs * g[i] + b[i];
        if (ACT == 1) v = gelu_f(v);
        o_[i] = v;
    }
}

// ---------------- register-tiled GEMM: C = act(A@B + bias) ----------------
// BM=128, BN=64, BK=16; 256 threads; 8x4 micro-tile per thread.
template<int ACT>
__global__ __launch_bounds__(256) void gemm_rt(const float* __restrict__ A, int lda,
                                               const float* __restrict__ B,
                                               const float* __restrict__ bias,
                                               float* __restrict__ C, int ldc,
                                               int M, int N, int K){
    __shared__ __align__(16) float As[16][132];   // [kk][m]
    __shared__ __align__(16) float Bs[16][68];    // [kk][n]
    int tid = threadIdx.x;
    int tx = tid & 15, ty = tid >> 4;
    int row0 = blockIdx.y * 128 + ty * 8;
    int col0 = blockIdx.x * 64 + tx * 4;
    float acc[8][4];
    #pragma unroll
    for (int i = 0; i < 8; i++)
        #pragma unroll
        for (int j = 0; j < 4; j++) acc[i][j] = 0.f;

    for (int k0 = 0; k0 < K; k0 += 16){
        #pragma unroll
        for (int i = 0; i < 8; i++){
            int e = tid + i * 256;
            int m = e >> 4, kk = e & 15;
            int r = blockIdx.y * 128 + m;
            As[kk][m] = (r < M && k0 + kk < K) ? A[(size_t)r * lda + k0 + kk] : 0.f;
        }
        #pragma unroll
        for (int i = 0; i < 4; i++){
            int e = tid + i * 256;
            int kk = e >> 6, n = e & 63;
            int c = blockIdx.x * 64 + n;
            Bs[kk][n] = (c < N && k0 + kk < K) ? B[(size_t)(k0 + kk) * N + c] : 0.f;
        }
        __syncthreads();
        #pragma unroll
        for (int kk = 0; kk < 16; kk++){
            float a[8], b[4];
            *reinterpret_cast<float4*>(&a[0]) = *reinterpret_cast<const float4*>(&As[kk][ty * 8]);
            *reinterpret_cast<float4*>(&a[4]) = *reinterpret_cast<const float4*>(&As[kk][ty * 8 + 4]);
            *reinterpret_cast<float4*>(&b[0]) = *reinterpret_cast<const float4*>(&Bs[kk][tx * 4]);
            #pragma unroll
            for (int i = 0; i < 8; i++)
                #pragma unroll
                for (int j = 0; j < 4; j++) acc[i][j] += a[i] * b[j];
        }
        __syncthreads();
    }
    #pragma unroll
    for (int i = 0; i < 8; i++){
        int r = row0 + i;
        if (r >= M) break;
        #pragma unroll
        for (int j = 0; j < 4; j++){
            int c = col0 + j;
            if (c < N){
                float v = acc[i][j] + (bias ? bias[c] : 0.f);
                if (ACT == 1) v = gelu_f(v);
                C[(size_t)r * ldc + c] = v;
            }
        }
    }
}

// ---------------- tiled direct conv 3x3, HWC in / HWC out partials --------------
// block: 16x16 output tile, all OC channels; thread = 2x2 quad x (OC/4) channels.
// blockIdx.z = ci-split; writes partial sums (no bias/act) to part[z][pix][OC].
template<int IC, int OC, int PAD, int CICHUNK, int NCHUNK, int TN>
__global__ __launch_bounds__(256) void conv_tiled(const float* __restrict__ in,
                                                  const float* __restrict__ w,
                                                  float* __restrict__ part,
                                                  int inH, int inW, int outH, int outW){
    const int XST = (CICHUNK % 2 == 0) ? CICHUNK + 1 : CICHUNK;
    __shared__ float xs[324 * XST];                 // [yy][xx][ci]
    __shared__ __align__(16) float ws[CICHUNK * 9 * OC]; // [ci][tap][o]
    int tid = threadIdx.x;
    int q = tid & 63, cg = tid >> 6;
    int qx = q & 7, qy = q >> 3;
    int X0 = blockIdx.x * 16, Y0 = blockIdx.y * 16;
    int lx0 = qx * 2, ly0 = qy * 2;
    int ch0 = cg * TN;
    int ci0 = blockIdx.z * (CICHUNK * NCHUNK);
    int outHW = outH * outW;

    float acc[2][2][TN];
    #pragma unroll
    for (int a = 0; a < 2; a++)
        #pragma unroll
        for (int b = 0; b < 2; b++)
            #pragma unroll
            for (int j = 0; j < TN; j++) acc[a][b][j] = 0.f;

    for (int ch = 0; ch < NCHUNK; ch++){
        int cib = ci0 + ch * CICHUNK;
        // stage input tile (coalesced: ci fastest)
        for (int e = tid; e < 324 * CICHUNK; e += 256){
            int ci = e % CICHUNK, rest = e / CICHUNK;
            int xx = rest % 18, yy = rest / 18;
            int iy = Y0 - PAD + yy, ix = X0 - PAD + xx;
            float v = 0.f;
            if ((unsigned)iy < (unsigned)inH && (unsigned)ix < (unsigned)inW)
                v = in[((size_t)iy * inW + ix) * IC + cib + ci];
            xs[(yy * 18 + xx) * XST + ci] = v;
        }
        // stage weights [ci][tap][o]
        for (int e = tid; e < CICHUNK * 9 * OC; e += 256){
            int o = e % OC, rest = e / OC;
            int tap = rest % 9, ci = rest / 9;
            ws[(ci * 9 + tap) * OC + o] = w[((size_t)o * IC + cib + ci) * 9 + tap];
        }
        __syncthreads();
        for (int ci = 0; ci < CICHUNK; ci++){
            float xv[4][4];
            #pragma unroll
            for (int r = 0; r < 4; r++)
                #pragma unroll
                for (int c = 0; c < 4; c++)
                    xv[r][c] = xs[((ly0 + r) * 18 + (lx0 + c)) * XST + ci];
            #pragma unroll
            for (int ky = 0; ky < 3; ky++)
                #pragma unroll
                for (int kx = 0; kx < 3; kx++){
                    const float* wrow = &ws[(ci * 9 + ky * 3 + kx) * OC + ch0];
                    float wr[TN];
                    #pragma unroll
                    for (int j = 0; j < TN; j += 4)
                        *reinterpret_cast<float4*>(&wr[j]) = *reinterpret_cast<const float4*>(&wrow[j]);
                    #pragma unroll
                    for (int j = 0; j < TN; j++){
                        acc[0][0][j] += xv[ky][kx]     * wr[j];
                        acc[0][1][j] += xv[ky][kx + 1] * wr[j];
                        acc[1][0][j] += xv[ky + 1][kx]     * wr[j];
                        acc[1][1][j] += xv[ky + 1][kx + 1] * wr[j];
                    }
                }
        }
        __syncthreads();
    }
    // write partials
    #pragma unroll
    for (int a = 0; a < 2; a++){
        int oy = Y0 + ly0 + a;
        if (oy >= outH) continue;
        #pragma unroll
        for (int b = 0; b < 2; b++){
            int ox = X0 + lx0 + b;
            if (ox >= outW) continue;
            size_t base = ((size_t)blockIdx.z * outHW + (size_t)oy * outW + ox) * OC + ch0;
            #pragma unroll
            for (int j = 0; j < TN; j += 4)
                *reinterpret_cast<float4*>(&part[base + j]) = *reinterpret_cast<const float4*>(&acc[a][b][j]);
        }
    }
}

// reduce partials + bias + gelu
template<int OC, int NSPLIT>
__global__ void conv_reduce(const float* __restrict__ part, const float* __restrict__ bias,
                            float* __restrict__ out, int outHW){
    int idx = blockIdx.x * 256 + threadIdx.x;
    if (idx >= outHW * OC) return;
    int o = idx & (OC - 1);
    float s = bias[o];
    #pragma unroll
    for (int z = 0; z < NSPLIT; z++) s += part[(size_t)z * outHW * OC + idx];
    out[idx] = gelu_f(s);
}

// ---------------- adaptive pool HWC (64,147,147)->(145,145,64) into comb[:,128:] ----
__global__ void pool_kernel(const float* __restrict__ c2, float* __restrict__ comb){
    int idx = blockIdx.x * 256 + threadIdx.x;
    if (idx >= HW * 64) return;
    int o = idx & 63;
    int pix = idx >> 6;
    int xo = pix % Wdim, yo = pix / Wdim;
    int ys = yo * CONVH / Hdim, ye = ((yo + 1) * CONVH + Hdim - 1) / Hdim;
    int xs = xo * CONVH / Wdim, xe = ((xo + 1) * CONVH + Wdim - 1) / Wdim;
    float s = 0.f;
    for (int yy = ys; yy < ye; yy++)
        for (int xx = xs; xx < xe; xx++)
            s += c2[((size_t)yy * CONVH + xx) * 64 + o];
    comb[(size_t)pix * 192 + 128 + o] = s / (float)((ye - ys) * (xe - xs));
}

// ---------------- dt = softplus(raw + bias) ----------------
__global__ void dt_kernel(const float* __restrict__ zx, const float* __restrict__ dt_bias,
                          float* __restrict__ dtb){
    int idx = blockIdx.x * 256 + threadIdx.x;
    if (idx >= HW * 4) return;
    int h = idx & 3, t = idx >> 2;
    float v = zx[(size_t)t * 772 + 768 + h] + dt_bias[h];
    dtb[idx] = (v > 20.f) ? v : log1pf(expf(v));
}

// ---------------- depthwise causal conv1d (width 4) + silu ----------------
__global__ void conv1d_kernel(const float* __restrict__ zx, const float* __restrict__ w,
                              const float* __restrict__ b, float* __restrict__ xbc){
    int c = blockIdx.x * 256 + threadIdx.x;
    int t = blockIdx.y;
    if (c >= 512) return;
    float acc = b[c];
    #pragma unroll
    for (int k = 0; k < 4; k++){
        int tt = t - 3 + k;
        if (tt < 0) continue;
        acc += zx[(size_t)tt * 772 + 256 + c] * w[c * 4 + k];
    }
    xbc[(size_t)t * 512 + c] = silu_f(acc);
}

// ---------------- chunk cumsum of a = dt*A (wave 0 scan) ----------------
__device__ __forceinline__ void chunk_cumsum(const float* __restrict__ dtb, int t0, int Q,
                                             int h, float A, float* cum, float* dth){
    int tid = threadIdx.x;
    if (tid < 64){
        float d = (tid < Q) ? dtb[(size_t)(t0 + tid) * 4 + h] : 0.f;
        dth[tid] = d;
        float a = d * A;
        #pragma unroll
        for (int off = 1; off < 64; off <<= 1){
            float u = __shfl_up(a, off);
            if (tid >= off) a += u;
        }
        cum[tid] = a;
    }
    __syncthreads();
}

// ---------------- SSD phase A: chunk-local end states ----------------
__global__ __launch_bounds__(256) void ssd_phaseA(const float* __restrict__ xbc,
                                                  const float* __restrict__ dtb,
                                                  const float* __restrict__ A_log,
                                                  float* __restrict__ S,
                                                  float* __restrict__ chunkT){
    __shared__ float cum[64], dth[64], w[64];
    __shared__ float Bw[32][128];
    __shared__ float Xs[32][64];
    int bid = blockIdx.x, c = bid >> 2, h = bid & 3;
    int t0 = c * QC, Q = min(QC, HW - t0);
    float A = -expf(A_log[h]);
    chunk_cumsum(dtb, t0, Q, h, A, cum, dth);
    int tid = threadIdx.x;
    float T = cum[Q - 1];
    if (tid == 0) chunkT[bid] = T;
    if (tid < 64) w[tid] = (tid < Q) ? __expf(T - cum[tid]) * dth[tid] : 0.f;
    __syncthreads();
    int n = tid >> 1, ph = tid & 1;
    float acc[32];
    #pragma unroll
    for (int j = 0; j < 32; j++) acc[j] = 0.f;
    for (int s0 = 0; s0 < QC; s0 += 32){
        for (int e = tid; e < 32 * 128; e += 256){
            int ss = e >> 7, nn = e & 127;
            int t = t0 + s0 + ss;
            Bw[ss][nn] = (s0 + ss < Q) ? xbc[(size_t)t * 512 + 256 + nn] * w[s0 + ss] : 0.f;
        }
        for (int e = tid; e < 32 * 64; e += 256){
            int ss = e >> 6, pp = e & 63;
            int t = t0 + s0 + ss;
            Xs[ss][pp] = (s0 + ss < Q) ? xbc[(size_t)t * 512 + h * 64 + pp] : 0.f;
        }
        __syncthreads();
        #pragma unroll 4
        for (int ss = 0; ss < 32; ss++){
            float bv = Bw[ss][n];
            #pragma unroll
            for (int j = 0; j < 32; j++) acc[j] += bv * Xs[ss][ph * 32 + j];
        }
        __syncthreads();
    }
    size_t base = ((size_t)bid * 128 + n) * 64 + ph * 32;
    #pragma unroll
    for (int j = 0; j < 32; j++) S[base + j] = acc[j];
}

// ---------------- SSD phase B: in-place prefix over chunks ----------------
__global__ void ssd_phaseB(float* __restrict__ S, const float* __restrict__ chunkT){
    int idx = blockIdx.x * 256 + threadIdx.x;   // 4*128*64 = 32768
    int h = idx >> 13;
    int inner = idx & 8191;
    float s = 0.f;
    for (int c = 0; c < NCH; c++){
        size_t off = ((size_t)(c * 4 + h)) * 8192 + inner;
        float loc = S[off];
        S[off] = s;                              // state BEFORE chunk c
        s = s * expf(chunkT[c * 4 + h]) + loc;
    }
}

// ---------------- SSD phase C: outputs ----------------
__global__ __launch_bounds__(256) void ssd_phaseC(const float* __restrict__ xbc,
                                                  const float* __restrict__ dtb,
                                                  const float* __restrict__ A_log,
                                                  const float* __restrict__ Dvec,
                                                  const float* __restrict__ S,
                                                  float* __restrict__ y){
    __shared__ float cum[64], dth[64];
    __shared__ float P[64][65];
    __shared__ float ubuf[4096];     // union: {Ct[64][17] | BtT[16][68] | SCt[16][64]}  OR  Xs[64][64]
    float* Ct  = ubuf;               // stride 17
    float* BtT = ubuf + 1088;        // stride 68
    float* SCt = ubuf + 2176;        // stride 64
    int bid = blockIdx.x, c = bid >> 2, h = bid & 3;
    int t0 = c * QC, Q = min(QC, HW - t0);
    float A = -expf(A_log[h]);
    chunk_cumsum(dtb, t0, Q, h, A, cum, dth);
    int tid = threadIdx.x;
    int t = tid >> 2, q = tid & 3;
    float acc[16], acc2[16];
    #pragma unroll
    for (int j = 0; j < 16; j++){ acc[j] = 0.f; acc2[j] = 0.f; }
    for (int n0 = 0; n0 < 128; n0 += 16){
        for (int e = tid; e < 1024; e += 256){
            int tt = e >> 4, nn = e & 15;
            Ct[tt * 17 + nn] = (tt < Q) ? xbc[(size_t)(t0 + tt) * 512 + 384 + n0 + nn] : 0.f;
        }
        for (int e = tid; e < 1024; e += 256){
            int tt = e >> 4, nn = e & 15;
            BtT[nn * 68 + tt] = (tt < Q) ? xbc[(size_t)(t0 + tt) * 512 + 256 + n0 + nn] : 0.f;
        }
        for (int e = tid; e < 1024; e += 256){
            int nn = e >> 6, pp = e & 63;
            SCt[nn * 64 + pp] = S[((size_t)bid * 128 + n0 + nn) * 64 + pp];
        }
        __syncthreads();
        #pragma unroll
        for (int nn = 0; nn < 16; nn++){
            float cv = Ct[t * 17 + nn];
            #pragma unroll
            for (int j = 0; j < 16; j++) acc[j]  += cv * BtT[nn * 68 + q * 16 + j];
            #pragma unroll
            for (int j = 0; j < 16; j++) acc2[j] += cv * SCt[nn * 64 + q * 16 + j];
        }
        __syncthreads();
    }
    float ct = cum[t];
    #pragma unroll
    for (int j = 0; j < 16; j++){
        int s = q * 16 + j;
        float pv = 0.f;
        if (s <= t && s < Q) pv = acc[j] * __expf(ct - cum[s]) * dth[s];
        P[t][s] = pv;
    }
    __syncthreads();
    for (int e = tid; e < 4096; e += 256){
        int ss = e >> 6, pp = e & 63;
        ubuf[e] = (ss < Q) ? xbc[(size_t)(t0 + ss) * 512 + h * 64 + pp] : 0.f;
    }
    __syncthreads();
    float ext = __expf(ct);
    float yacc[16];
    #pragma unroll
    for (int j = 0; j < 16; j++) yacc[j] = ext * acc2[j];
    for (int s = 0; s < 64; s++){
        float pv = P[t][s];
        #pragma unroll
        for (int j = 0; j < 16; j++) yacc[j] += pv * ubuf[s * 64 + q * 16 + j];
    }
    if (t < Q){
        float Dh = Dvec[h];
        size_t yb = (size_t)(t0 + t) * 256 + h * 64 + q * 16;
        #pragma unroll
        for (int j = 0; j < 16; j++) y[yb + j] = yacc[j] + Dh * ubuf[t * 64 + q * 16 + j];
    }
}

// ---------------- gated RMSNorm ----------------
__global__ void gated_rms_kernel(float* __restrict__ y, const float* __restrict__ zx,
                                 const float* __restrict__ nw){
    int row = blockIdx.x, tid = threadIdx.x;
    float v = y[(size_t)row * 256 + tid];
    float z = zx[(size_t)row * 772 + tid];
    v *= silu_f(z);
    float s = v * v;
    __shared__ float r1[4];
    #pragma unroll
    for (int o = 32; o > 0; o >>= 1) s += __shfl_down(s, o);
    if ((tid & 63) == 0) r1[tid >> 6] = s;
    __syncthreads();
    float S = r1[0] + r1[1] + r1[2] + r1[3];
    float rs = rsqrtf(S / 256.f + 1e-5f);
    y[(size_t)row * 256 + tid] = v * rs * nw[tid];
}

extern "C" void kernel_launch(void* const* d_in, const int* in_sizes, int n_in,
                              void* d_out, int out_size, void* d_ws, size_t ws_size,
                              hipStream_t stream){
    (void)in_sizes; (void)n_in; (void)out_size; (void)ws_size;
    const float* x        = (const float*)d_in[0];
    const float* ln_pre_g = (const float*)d_in[1];
    const float* ln_pre_b = (const float*)d_in[2];
    const float* fe_w1    = (const float*)d_in[3];
    const float* fe_b1    = (const float*)d_in[4];
    const float* fe_w2    = (const float*)d_in[5];
    const float* fe_b2    = (const float*)d_in[6];
    const float* cv_w1    = (const float*)d_in[7];
    const float* cv_b1    = (const float*)d_in[8];
    const float* cv_w2    = (const float*)d_in[9];
    const float* cv_b2    = (const float*)d_in[10];
    const float* mp_w     = (const float*)d_in[11];
    const float* mp_b     = (const float*)d_in[12];
    const float* mp_ln_g  = (const float*)d_in[13];
    const float* mp_ln_b  = (const float*)d_in[14];
    const float* m_in_w   = (const float*)d_in[15];
    const float* m_conv_w = (const float*)d_in[16];
    const float* m_conv_b = (const float*)d_in[17];
    const float* m_dtb    = (const float*)d_in[18];
    const float* m_A_log  = (const float*)d_in[19];
    const float* m_D      = (const float*)d_in[20];
    const float* m_norm_w = (const float*)d_in[21];
    const float* m_out_w  = (const float*)d_in[22];
    const float* cls_ln_g = (const float*)d_in[23];
    const float* cls_ln_b = (const float*)d_in[24];
    const float* cls_w1   = (const float*)d_in[25];
    const float* cls_b1   = (const float*)d_in[26];
    const float* cls_w2   = (const float*)d_in[27];
    const float* cls_b2   = (const float*)d_in[28];
    const float* cls_w3   = (const float*)d_in[29];
    const float* cls_b3   = (const float*)d_in[30];

    float* ws   = (float*)d_ws;
    float* xn   = ws + OFF_XN;
    float* f1   = ws + OFF_F1;
    float* comb = ws + OFF_COMB;
    float* p    = ws + OFF_P;
    float* zx   = ws + OFF_ZX;
    float* xbc  = ws + OFF_XBC;
    float* Sbuf = ws + OFF_S;
    float* dtb  = ws + OFF_DT;
    float* chkT = ws + OFF_CT;
    // region reuse
    float* convpart = ws + OFF_S;                 // before S is live
    float* c1h  = ws + OFF_XBC;                   // before xbc is live
    float* c2h  = ws + OFF_XBC + 691488;
    float* pr   = ws + OFF_XN;                    // xn dead after conv1
    float* ybuf = ws + OFF_F1;                    // f1 dead after fe2
    float* mo   = ws + OFF_COMB;                  // comb dead after mp
    float* cls0 = ws + OFF_XN;
    float* cls1 = ws + OFF_P;                     // p dead after in-proj
    float* cls2 = ws + OFF_COMB + 2691200;

    // 1. pre-LN
    ln_kernel<0><<<HW, 256, 0, stream>>>(x, ln_pre_g, ln_pre_b, xn, NBANDS);
    // 2-3. feature MLP (f -> comb[:, :128], ldc=192)
    gemm_rt<1><<<dim3(4, 165), 256, 0, stream>>>(xn, 200, fe_w1, fe_b1, f1, 256, HW, 256, 200);
    gemm_rt<1><<<dim3(2, 165), 256, 0, stream>>>(f1, 256, fe_w2, fe_b2, comb, 192, HW, 128, 256);
    // 4. conv1: 200->32, pad 2 (HWC in/out), ci-split 4
    conv_tiled<200, 32, 2, 25, 2, 8><<<dim3(10, 10, 4), 256, 0, stream>>>(xn, cv_w1, convpart, Hdim, Wdim, CONVH, CONVH);
    conv_reduce<32, 4><<<(CONVHW * 32 + 255) / 256, 256, 0, stream>>>(convpart, cv_b1, c1h, CONVHW);
    // 5. conv2: 32->64, pad 1, ci-split 2
    conv_tiled<32, 64, 1, 16, 1, 16><<<dim3(10, 10, 2), 256, 0, stream>>>(c1h, cv_w2, convpart, CONVH, CONVH, CONVH, CONVH);
    conv_reduce<64, 2><<<(CONVHW * 64 + 255) / 256, 256, 0, stream>>>(convpart, cv_b2, c2h, CONVHW);
    // 6. adaptive pool -> comb[:, 128:192]
    pool_kernel<<<(HW * 64 + 255) / 256, 256, 0, stream>>>(c2h, comb);
    // 7-8. mid projection + LN + GELU
    gemm_rt<0><<<dim3(2, 165), 256, 0, stream>>>(comb, 192, mp_w, mp_b, pr, 128, HW, 128, 192);
    ln_kernel<1><<<HW, 256, 0, stream>>>(pr, mp_ln_g, mp_ln_b, p, 128);
    // 9. mamba in_proj
    gemm_rt<0><<<dim3(13, 165), 256, 0, stream>>>(p, 128, m_in_w, (const float*)nullptr, zx, 772, HW, 772, 128);
    // 10. dt softplus
    dt_kernel<<<(HW * 4 + 255) / 256, 256, 0, stream>>>(zx, m_dtb, dtb);
    // 11. depthwise causal conv + silu
    conv1d_kernel<<<dim3(2, HW), 256, 0, stream>>>(zx, m_conv_w, m_conv_b, xbc);
    // 12-14. SSD chunked scan
    ssd_phaseA<<<NCH * 4, 256, 0, stream>>>(xbc, dtb, m_A_log, Sbuf, chkT);
    ssd_phaseB<<<128, 256, 0, stream>>>(Sbuf, chkT);
    ssd_phaseC<<<NCH * 4, 256, 0, stream>>>(xbc, dtb, m_A_log, m_D, Sbuf, ybuf);
    // 15. gated RMSNorm
    gated_rms_kernel<<<HW, 256, 0, stream>>>(ybuf, zx, m_norm_w);
    // 16. out proj
    gemm_rt<0><<<dim3(2, 165), 256, 0, stream>>>(ybuf, 256, m_out_w, (const float*)nullptr, mo, 128, HW, 128, 256);
    // 17-20. classifier
    ln_kernel<0><<<HW, 256, 0, stream>>>(mo, cls_ln_g, cls_ln_b, cls0, 128);
    gemm_rt<1><<<dim3(2, 165), 256, 0, stream>>>(cls0, 128, cls_w1, cls_b1, cls1, 128, HW, 128, 128);
    gemm_rt<1><<<dim3(1, 165), 256, 0, stream>>>(cls1, 128, cls_w2, cls_b2, cls2, 64, HW, 64, 128);
    gemm_rt<0><<<dim3(1, 165), 256, 0, stream>>>(cls2, 64, cls_w3, cls_b3, (float*)d_out, 17, HW, 17, 64);
}

// Round 3
// 709.288 us; speedup vs baseline: 2.6362x; 1.2980x over previous
//
#include <hip/hip_runtime.h>
#include <math.h>

#define HW 21025        // 145*145
#define Hdim 145
#define Wdim 145
#define NBANDS 200
#define CONVH 147
#define CONVHW 21609    // 147*147
#define QC 64
#define NCH 329         // ceil(21025/64)

typedef __attribute__((ext_vector_type(4))) float fv4;
typedef __attribute__((ext_vector_type(8))) short short8;

// ---------------- workspace layout (float offsets) ----------------
#define OFF_XN   ((size_t)0)           // 4,205,000  xn; later pr, cls0
#define OFF_F1   ((size_t)4205000)     // 5,382,400  f1; later y (L x 256)
#define OFF_COMB ((size_t)9587400)     // 4,036,800  comb L x 192; later mo + cls2
#define OFF_P    ((size_t)13624200)    // 2,691,200  p; later cls1
#define OFF_ZX   ((size_t)16315400)    // 16,231,300 zxbcdt L x 772
#define OFF_XBC  ((size_t)32546700)    // 10,764,800 c1h+c2h first, then xbc L x 512
#define OFF_S    ((size_t)43311500)    // 10,780,672 convpart first, then S
#define OFF_DT   ((size_t)54092172)    // 84,100
#define OFF_CT   ((size_t)54176272)    // 1,316

__device__ __forceinline__ float gelu_f(float x){
    return 0.5f * x * (1.0f + erff(x * 0.70710678118654752440f));
}
__device__ __forceinline__ float silu_f(float x){
    return x / (1.0f + expf(-x));
}
__device__ __forceinline__ unsigned f32bits(float x){ return __float_as_uint(x); }

// split f32 -> (hi, lo) bf16 pair; hi = truncate, lo = truncate(x - hi)
__device__ __forceinline__ void bf16_split(float x, unsigned short& hs, unsigned short& ls){
    unsigned u = __float_as_uint(x);
    hs = (unsigned short)(u >> 16);
    float hif = __uint_as_float(u & 0xFFFF0000u);
    float lof = x - hif;
    ls = (unsigned short)(__float_as_uint(lof) >> 16);
}

// ---------------- LayerNorm (+ optional GELU) ----------------
template<int ACT>
__global__ void ln_kernel(const float* __restrict__ in, const float* __restrict__ g,
                          const float* __restrict__ b, float* __restrict__ out, int D){
    int row = blockIdx.x, tid = threadIdx.x;
    const float* r = in + (size_t)row * D;
    float s = 0.f, s2 = 0.f;
    for (int i = tid; i < D; i += 256){ float v = r[i]; s += v; s2 += v*v; }
    __shared__ float r1[4], r2[4];
    #pragma unroll
    for (int o = 32; o > 0; o >>= 1){ s += __shfl_down(s, o); s2 += __shfl_down(s2, o); }
    if ((tid & 63) == 0){ r1[tid >> 6] = s; r2[tid >> 6] = s2; }
    __syncthreads();
    float S = r1[0] + r1[1] + r1[2] + r1[3];
    float S2 = r2[0] + r2[1] + r2[2] + r2[3];
    float mean = S / (float)D;
    float var = S2 / (float)D - mean * mean;
    float rs = rsqrtf(fmaxf(var, 0.f) + 1e-5f);
    float* o_ = out + (size_t)row * D;
    for (int i = tid; i < D; i += 256){
        float v = (r[i] - mean) * rs * g[i] + b[i];
        if (ACT == 1) v = gelu_f(v);
        o_[i] = v;
    }
}

// ---------------- split-bf16 MFMA GEMM: C = act(A@B + bias) ----------------
// BM=128, BN=64, BK=32; 256 threads = 4 waves in 2x2; per wave 64x32 out.
// A,B split to bf16 hi/lo; D = Ah.Bh + Ah.Bl + Al.Bh (f32 acc) ~ f32 precision.
template<int ACT>
__global__ __launch_bounds__(256) void gemm_mfma(const float* __restrict__ A, int lda,
                                                 const float* __restrict__ B,
                                                 const float* __restrict__ bias,
                                                 float* __restrict__ C, int ldc,
                                                 int M, int N, int K){
    const int SA = 40;   // short stride per row (2-way bank alias only)
    __shared__ __align__(16) unsigned short Ah[128 * SA], Al[128 * SA];
    __shared__ __align__(16) unsigned short Bh[64 * SA],  Bl[64 * SA];
    int tid = threadIdx.x;
    int lane = tid & 63, wid = tid >> 6;
    int wy = wid >> 1, wx = wid & 1;
    int bm = blockIdx.y * 128, bn = blockIdx.x * 64;
    int l15 = lane & 15, g = lane >> 4;

    fv4 acc[4][2];
    #pragma unroll
    for (int i = 0; i < 4; i++)
        #pragma unroll
        for (int j = 0; j < 2; j++) acc[i][j] = (fv4){0.f,0.f,0.f,0.f};

    // staging maps
    int am = tid >> 1;                 // 0..127 row
    int aq = (tid & 1) * 4;            // float4 index base (0 or 4)
    bool arow_ok = (bm + am) < M;
    int bn_t = tid & 63;               // 0..63 col of B-tile
    int bk8 = (tid >> 6) * 8;          // 8 consecutive k
    bool bcol_ok = (bn + bn_t) < N;

    int nK = (K + 31) / 32;
    for (int ks = 0; ks < nK; ks++){
        int k0 = ks * 32;
        // ---- stage A (4 x float4 per thread) ----
        const float* Ap = A + (size_t)(bm + am) * lda + k0;
        #pragma unroll
        for (int f = 0; f < 4; f++){
            int kq = aq + f;
            fv4 v = (fv4){0.f,0.f,0.f,0.f};
            if (arow_ok && (k0 + kq * 4 + 4) <= K)
                v = *reinterpret_cast<const fv4*>(Ap + kq * 4);
            unsigned short hs[4], ls[4];
            #pragma unroll
            for (int j = 0; j < 4; j++) bf16_split(v[j], hs[j], ls[j]);
            unsigned off = am * SA + kq * 4;
            *reinterpret_cast<uint2*>(&Ah[off]) =
                make_uint2((unsigned)hs[0] | ((unsigned)hs[1] << 16),
                           (unsigned)hs[2] | ((unsigned)hs[3] << 16));
            *reinterpret_cast<uint2*>(&Al[off]) =
                make_uint2((unsigned)ls[0] | ((unsigned)ls[1] << 16),
                           (unsigned)ls[2] | ((unsigned)ls[3] << 16));
        }
        // ---- stage B transposed: Bs[n][k] (8 scalar loads -> one b128 write) ----
        {
            unsigned short hs[8], ls[8];
            #pragma unroll
            for (int j = 0; j < 8; j++){
                int kk = k0 + bk8 + j;
                float v = (bcol_ok && kk < K) ? B[(size_t)kk * N + bn + bn_t] : 0.f;
                bf16_split(v, hs[j], ls[j]);
            }
            unsigned off = bn_t * SA + bk8;
            *reinterpret_cast<uint4*>(&Bh[off]) =
                make_uint4((unsigned)hs[0] | ((unsigned)hs[1] << 16),
                           (unsigned)hs[2] | ((unsigned)hs[3] << 16),
                           (unsigned)hs[4] | ((unsigned)hs[5] << 16),
                           (unsigned)hs[6] | ((unsigned)hs[7] << 16));
            *reinterpret_cast<uint4*>(&Bl[off]) =
                make_uint4((unsigned)ls[0] | ((unsigned)ls[1] << 16),
                           (unsigned)ls[2] | ((unsigned)ls[3] << 16),
                           (unsigned)ls[4] | ((unsigned)ls[5] << 16),
                           (unsigned)ls[6] | ((unsigned)ls[7] << 16));
        }
        __syncthreads();
        // ---- fragments + MFMA ----
        short8 afh[4], afl[4], bfh[2], bfl[2];
        #pragma unroll
        for (int mi = 0; mi < 4; mi++){
            unsigned off = (wy * 64 + mi * 16 + l15) * SA + g * 8;
            afh[mi] = *reinterpret_cast<const short8*>(&Ah[off]);
            afl[mi] = *reinterpret_cast<const short8*>(&Al[off]);
        }
        #pragma unroll
        for (int ni = 0; ni < 2; ni++){
            unsigned off = (wx * 32 + ni * 16 + l15) * SA + g * 8;
            bfh[ni] = *reinterpret_cast<const short8*>(&Bh[off]);
            bfl[ni] = *reinterpret_cast<const short8*>(&Bl[off]);
        }
        #pragma unroll
        for (int mi = 0; mi < 4; mi++)
            #pragma unroll
            for (int ni = 0; ni < 2; ni++){
                acc[mi][ni] = __builtin_amdgcn_mfma_f32_16x16x32_bf16(afh[mi], bfh[ni], acc[mi][ni], 0, 0, 0);
                acc[mi][ni] = __builtin_amdgcn_mfma_f32_16x16x32_bf16(afh[mi], bfl[ni], acc[mi][ni], 0, 0, 0);
                acc[mi][ni] = __builtin_amdgcn_mfma_f32_16x16x32_bf16(afl[mi], bfh[ni], acc[mi][ni], 0, 0, 0);
            }
        __syncthreads();
    }
    // ---- epilogue: C/D layout col=lane&15, row=(lane>>4)*4+reg ----
    #pragma unroll
    for (int mi = 0; mi < 4; mi++){
        #pragma unroll
        for (int ni = 0; ni < 2; ni++){
            int cc = bn + wx * 32 + ni * 16 + l15;
            if (cc >= N) continue;
            float bv = bias ? bias[cc] : 0.f;
            #pragma unroll
            for (int j = 0; j < 4; j++){
                int rr = bm + wy * 64 + mi * 16 + g * 4 + j;
                if (rr >= M) continue;
                float v = acc[mi][ni][j] + bv;
                if (ACT == 1) v = gelu_f(v);
                C[(size_t)rr * ldc + cc] = v;
            }
        }
    }
}

// ---------------- tiled direct conv 3x3, HWC in / HWC out partials --------------
template<int IC, int OC, int PAD, int CICHUNK, int NCHUNK, int TN>
__global__ __launch_bounds__(256) void conv_tiled(const float* __restrict__ in,
                                                  const float* __restrict__ w,
                                                  float* __restrict__ part,
                                                  int inH, int inW, int outH, int outW){
    const int XST = (CICHUNK % 2 == 0) ? CICHUNK + 1 : CICHUNK;
    __shared__ float xs[324 * XST];
    __shared__ __align__(16) float ws[CICHUNK * 9 * OC];
    int tid = threadIdx.x;
    int q = tid & 63, cg = tid >> 6;
    int qx = q & 7, qy = q >> 3;
    int X0 = blockIdx.x * 16, Y0 = blockIdx.y * 16;
    int lx0 = qx * 2, ly0 = qy * 2;
    int ch0 = cg * TN;
    int ci0 = blockIdx.z * (CICHUNK * NCHUNK);
    int outHW = outH * outW;

    float acc[2][2][TN];
    #pragma unroll
    for (int a = 0; a < 2; a++)
        #pragma unroll
        for (int b = 0; b < 2; b++)
            #pragma unroll
            for (int j = 0; j < TN; j++) acc[a][b][j] = 0.f;

    for (int ch = 0; ch < NCHUNK; ch++){
        int cib = ci0 + ch * CICHUNK;
        for (int e = tid; e < 324 * CICHUNK; e += 256){
            int ci = e % CICHUNK, rest = e / CICHUNK;
            int xx = rest % 18, yy = rest / 18;
            int iy = Y0 - PAD + yy, ix = X0 - PAD + xx;
            float v = 0.f;
            if ((unsigned)iy < (unsigned)inH && (unsigned)ix < (unsigned)inW)
                v = in[((size_t)iy * inW + ix) * IC + cib + ci];
            xs[(yy * 18 + xx) * XST + ci] = v;
        }
        for (int e = tid; e < CICHUNK * 9 * OC; e += 256){
            int o = e % OC, rest = e / OC;
            int tap = rest % 9, ci = rest / 9;
            ws[(ci * 9 + tap) * OC + o] = w[((size_t)o * IC + cib + ci) * 9 + tap];
        }
        __syncthreads();
        for (int ci = 0; ci < CICHUNK; ci++){
            float xv[4][4];
            #pragma unroll
            for (int r = 0; r < 4; r++)
                #pragma unroll
                for (int c = 0; c < 4; c++)
                    xv[r][c] = xs[((ly0 + r) * 18 + (lx0 + c)) * XST + ci];
            #pragma unroll
            for (int ky = 0; ky < 3; ky++)
                #pragma unroll
                for (int kx = 0; kx < 3; kx++){
                    const float* wrow = &ws[(ci * 9 + ky * 3 + kx) * OC + ch0];
                    float wr[TN];
                    #pragma unroll
                    for (int j = 0; j < TN; j += 4)
                        *reinterpret_cast<fv4*>(&wr[j]) = *reinterpret_cast<const fv4*>(&wrow[j]);
                    #pragma unroll
                    for (int j = 0; j < TN; j++){
                        acc[0][0][j] += xv[ky][kx]     * wr[j];
                        acc[0][1][j] += xv[ky][kx + 1] * wr[j];
                        acc[1][0][j] += xv[ky + 1][kx]     * wr[j];
                        acc[1][1][j] += xv[ky + 1][kx + 1] * wr[j];
                    }
                }
        }
        __syncthreads();
    }
    #pragma unroll
    for (int a = 0; a < 2; a++){
        int oy = Y0 + ly0 + a;
        if (oy >= outH) continue;
        #pragma unroll
        for (int b = 0; b < 2; b++){
            int ox = X0 + lx0 + b;
            if (ox >= outW) continue;
            size_t base = ((size_t)blockIdx.z * outHW + (size_t)oy * outW + ox) * OC + ch0;
            #pragma unroll
            for (int j = 0; j < TN; j += 4)
                *reinterpret_cast<fv4*>(&part[base + j]) = *reinterpret_cast<const fv4*>(&acc[a][b][j]);
        }
    }
}

template<int OC, int NSPLIT>
__global__ void conv_reduce(const float* __restrict__ part, const float* __restrict__ bias,
                            float* __restrict__ out, int outHW){
    int idx = blockIdx.x * 256 + threadIdx.x;
    if (idx >= outHW * OC) return;
    int o = idx & (OC - 1);
    float s = bias[o];
    #pragma unroll
    for (int z = 0; z < NSPLIT; z++) s += part[(size_t)z * outHW * OC + idx];
    out[idx] = gelu_f(s);
}

// ---------------- adaptive pool HWC into comb[:,128:] ----------------
__global__ void pool_kernel(const float* __restrict__ c2, float* __restrict__ comb){
    int idx = blockIdx.x * 256 + threadIdx.x;
    if (idx >= HW * 64) return;
    int o = idx & 63;
    int pix = idx >> 6;
    int xo = pix % Wdim, yo = pix / Wdim;
    int ys = yo * CONVH / Hdim, ye = ((yo + 1) * CONVH + Hdim - 1) / Hdim;
    int xs = xo * CONVH / Wdim, xe = ((xo + 1) * CONVH + Wdim - 1) / Wdim;
    float s = 0.f;
    for (int yy = ys; yy < ye; yy++)
        for (int xx = xs; xx < xe; xx++)
            s += c2[((size_t)yy * CONVH + xx) * 64 + o];
    comb[(size_t)pix * 192 + 128 + o] = s / (float)((ye - ys) * (xe - xs));
}

// ---------------- dt = softplus(raw + bias) ----------------
__global__ void dt_kernel(const float* __restrict__ zx, const float* __restrict__ dt_bias,
                          float* __restrict__ dtb){
    int idx = blockIdx.x * 256 + threadIdx.x;
    if (idx >= HW * 4) return;
    int h = idx & 3, t = idx >> 2;
    float v = zx[(size_t)t * 772 + 768 + h] + dt_bias[h];
    dtb[idx] = (v > 20.f) ? v : log1pf(expf(v));
}

// ---------------- depthwise causal conv1d (width 4) + silu ----------------
__global__ void conv1d_kernel(const float* __restrict__ zx, const float* __restrict__ w,
                              const float* __restrict__ b, float* __restrict__ xbc){
    int c = blockIdx.x * 256 + threadIdx.x;
    int t = blockIdx.y;
    if (c >= 512) return;
    float acc = b[c];
    #pragma unroll
    for (int k = 0; k < 4; k++){
        int tt = t - 3 + k;
        if (tt < 0) continue;
        acc += zx[(size_t)tt * 772 + 256 + c] * w[c * 4 + k];
    }
    xbc[(size_t)t * 512 + c] = silu_f(acc);
}

// ---------------- chunk cumsum of a = dt*A (wave 0 scan) ----------------
__device__ __forceinline__ void chunk_cumsum(const float* __restrict__ dtb, int t0, int Q,
                                             int h, float A, float* cum, float* dth){
    int tid = threadIdx.x;
    if (tid < 64){
        float d = (tid < Q) ? dtb[(size_t)(t0 + tid) * 4 + h] : 0.f;
        dth[tid] = d;
        float a = d * A;
        #pragma unroll
        for (int off = 1; off < 64; off <<= 1){
            float u = __shfl_up(a, off);
            if (tid >= off) a += u;
        }
        cum[tid] = a;
    }
    __syncthreads();
}

// ---------------- SSD phase A: chunk-local end states ----------------
__global__ __launch_bounds__(256) void ssd_phaseA(const float* __restrict__ xbc,
                                                  const float* __restrict__ dtb,
                                                  const float* __restrict__ A_log,
                                                  float* __restrict__ S,
                                                  float* __restrict__ chunkT){
    __shared__ float cum[64], dth[64], w[64];
    __shared__ float Bw[32][128];
    __shared__ float Xs[32][64];
    int bid = blockIdx.x, c = bid >> 2, h = bid & 3;
    int t0 = c * QC, Q = min(QC, HW - t0);
    float A = -expf(A_log[h]);
    chunk_cumsum(dtb, t0, Q, h, A, cum, dth);
    int tid = threadIdx.x;
    float T = cum[Q - 1];
    if (tid == 0) chunkT[bid] = T;
    if (tid < 64) w[tid] = (tid < Q) ? __expf(T - cum[tid]) * dth[tid] : 0.f;
    __syncthreads();
    int n = tid >> 1, ph = tid & 1;
    fv4 acc4[8];
    #pragma unroll
    for (int j = 0; j < 8; j++) acc4[j] = (fv4){0.f,0.f,0.f,0.f};
    for (int s0 = 0; s0 < QC; s0 += 32){
        for (int e = tid; e < 32 * 128; e += 256){
            int ss = e >> 7, nn = e & 127;
            int t = t0 + s0 + ss;
            Bw[ss][nn] = (s0 + ss < Q) ? xbc[(size_t)t * 512 + 256 + nn] * w[s0 + ss] : 0.f;
        }
        for (int e = tid; e < 32 * 64; e += 256){
            int ss = e >> 6, pp = e & 63;
            int t = t0 + s0 + ss;
            Xs[ss][pp] = (s0 + ss < Q) ? xbc[(size_t)t * 512 + h * 64 + pp] : 0.f;
        }
        __syncthreads();
        #pragma unroll 4
        for (int ss = 0; ss < 32; ss++){
            float bv = Bw[ss][n];
            const fv4* Xp = reinterpret_cast<const fv4*>(&Xs[ss][ph * 32]);
            #pragma unroll
            for (int jf = 0; jf < 8; jf++) acc4[jf] += bv * Xp[jf];
        }
        __syncthreads();
    }
    size_t base = ((size_t)bid * 128 + n) * 64 + ph * 32;
    #pragma unroll
    for (int jf = 0; jf < 8; jf++)
        *reinterpret_cast<fv4*>(&S[base + jf * 4]) = acc4[jf];
}

// ---------------- SSD phase B: in-place prefix over chunks ----------------
__global__ void ssd_phaseB(float* __restrict__ S, const float* __restrict__ chunkT){
    int idx = blockIdx.x * 256 + threadIdx.x;
    int h = idx >> 13;
    int inner = idx & 8191;
    float s = 0.f;
    for (int c = 0; c < NCH; c++){
        size_t off = ((size_t)(c * 4 + h)) * 8192 + inner;
        float loc = S[off];
        S[off] = s;
        s = s * expf(chunkT[c * 4 + h]) + loc;
    }
}

// ---------------- SSD phase C: outputs ----------------
__global__ __launch_bounds__(256) void ssd_phaseC(const float* __restrict__ xbc,
                                                  const float* __restrict__ dtb,
                                                  const float* __restrict__ A_log,
                                                  const float* __restrict__ Dvec,
                                                  const float* __restrict__ S,
                                                  float* __restrict__ y){
    __shared__ float cum[64], dth[64];
    __shared__ float P[64][65];
    __shared__ __align__(16) float ubuf[4096];  // {Ct[64][17] | BtT[16][80] | SCt[16][64]} OR Xs[64][64]
    float* Ct  = ubuf;               // stride 17
    float* BtT = ubuf + 1088;        // stride 80
    float* SCt = ubuf + 2368;        // stride 64
    int bid = blockIdx.x, c = bid >> 2, h = bid & 3;
    int t0 = c * QC, Q = min(QC, HW - t0);
    float A = -expf(A_log[h]);
    chunk_cumsum(dtb, t0, Q, h, A, cum, dth);
    int tid = threadIdx.x;
    int t = tid >> 2, q = tid & 3;
    fv4 a4[4], c4[4];
    #pragma unroll
    for (int j = 0; j < 4; j++){ a4[j] = (fv4){0.f,0.f,0.f,0.f}; c4[j] = (fv4){0.f,0.f,0.f,0.f}; }
    for (int n0 = 0; n0 < 128; n0 += 16){
        for (int e = tid; e < 1024; e += 256){
            int tt = e >> 4, nn = e & 15;
            Ct[tt * 17 + nn] = (tt < Q) ? xbc[(size_t)(t0 + tt) * 512 + 384 + n0 + nn] : 0.f;
        }
        for (int e = tid; e < 1024; e += 256){
            int tt = e >> 4, nn = e & 15;
            BtT[nn * 80 + tt] = (tt < Q) ? xbc[(size_t)(t0 + tt) * 512 + 256 + n0 + nn] : 0.f;
        }
        for (int e = tid; e < 1024; e += 256){
            int nn = e >> 6, pp = e & 63;
            SCt[nn * 64 + pp] = S[((size_t)bid * 128 + n0 + nn) * 64 + pp];
        }
        __syncthreads();
        #pragma unroll
        for (int nn = 0; nn < 16; nn++){
            float cv = Ct[t * 17 + nn];
            const fv4* Bp = reinterpret_cast<const fv4*>(&BtT[nn * 80 + q * 16]);
            const fv4* Sp = reinterpret_cast<const fv4*>(&SCt[nn * 64 + q * 16]);
            #pragma unroll
            for (int jf = 0; jf < 4; jf++){ a4[jf] += cv * Bp[jf]; c4[jf] += cv * Sp[jf]; }
        }
        __syncthreads();
    }
    float ct = cum[t];
    #pragma unroll
    for (int j = 0; j < 16; j++){
        int s = q * 16 + j;
        float pv = 0.f;
        if (s <= t && s < Q) pv = a4[j >> 2][j & 3] * __expf(ct - cum[s]) * dth[s];
        P[t][s] = pv;
    }
    __syncthreads();
    for (int e = tid; e < 4096; e += 256){
        int ss = e >> 6, pp = e & 63;
        ubuf[e] = (ss < Q) ? xbc[(size_t)(t0 + ss) * 512 + h * 64 + pp] : 0.f;
    }
    __syncthreads();
    float ext = __expf(ct);
    fv4 yacc[4];
    #pragma unroll
    for (int jf = 0; jf < 4; jf++) yacc[jf] = ext * c4[jf];
    for (int s = 0; s < 64; s++){
        float pv = P[t][s];
        const fv4* Xp = reinterpret_cast<const fv4*>(&ubuf[s * 64 + q * 16]);
        #pragma unroll
        for (int jf = 0; jf < 4; jf++) yacc[jf] += pv * Xp[jf];
    }
    if (t < Q){
        float Dh = Dvec[h];
        size_t yb = (size_t)(t0 + t) * 256 + h * 64 + q * 16;
        const fv4* Xt = reinterpret_cast<const fv4*>(&ubuf[t * 64 + q * 16]);
        #pragma unroll
        for (int jf = 0; jf < 4; jf++){
            fv4 v = yacc[jf] + Dh * Xt[jf];
            *reinterpret_cast<fv4*>(&y[yb + jf * 4]) = v;
        }
    }
}

// ---------------- gated RMSNorm ----------------
__global__ void gated_rms_kernel(float* __restrict__ y, const float* __restrict__ zx,
                                 const float* __restrict__ nw){
    int row = blockIdx.x, tid = threadIdx.x;
    float v = y[(size_t)row * 256 + tid];
    float z = zx[(size_t)row * 772 + tid];
    v *= silu_f(z);
    float s = v * v;
    __shared__ float r1[4];
    #pragma unroll
    for (int o = 32; o > 0; o >>= 1) s += __shfl_down(s, o);
    if ((tid & 63) == 0) r1[tid >> 6] = s;
    __syncthreads();
    float S = r1[0] + r1[1] + r1[2] + r1[3];
    float rs = rsqrtf(S / 256.f + 1e-5f);
    y[(size_t)row * 256 + tid] = v * rs * nw[tid];
}

extern "C" void kernel_launch(void* const* d_in, const int* in_sizes, int n_in,
                              void* d_out, int out_size, void* d_ws, size_t ws_size,
                              hipStream_t stream){
    (void)in_sizes; (void)n_in; (void)out_size; (void)ws_size;
    const float* x        = (const float*)d_in[0];
    const float* ln_pre_g = (const float*)d_in[1];
    const float* ln_pre_b = (const float*)d_in[2];
    const float* fe_w1    = (const float*)d_in[3];
    const float* fe_b1    = (const float*)d_in[4];
    const float* fe_w2    = (const float*)d_in[5];
    const float* fe_b2    = (const float*)d_in[6];
    const float* cv_w1    = (const float*)d_in[7];
    const float* cv_b1    = (const float*)d_in[8];
    const float* cv_w2    = (const float*)d_in[9];
    const float* cv_b2    = (const float*)d_in[10];
    const float* mp_w     = (const float*)d_in[11];
    const float* mp_b     = (const float*)d_in[12];
    const float* mp_ln_g  = (const float*)d_in[13];
    const float* mp_ln_b  = (const float*)d_in[14];
    const float* m_in_w   = (const float*)d_in[15];
    const float* m_conv_w = (const float*)d_in[16];
    const float* m_conv_b = (const float*)d_in[17];
    const float* m_dtb    = (const float*)d_in[18];
    const float* m_A_log  = (const float*)d_in[19];
    const float* m_D      = (const float*)d_in[20];
    const float* m_norm_w = (const float*)d_in[21];
    const float* m_out_w  = (const float*)d_in[22];
    const float* cls_ln_g = (const float*)d_in[23];
    const float* cls_ln_b = (const float*)d_in[24];
    const float* cls_w1   = (const float*)d_in[25];
    const float* cls_b1   = (const float*)d_in[26];
    const float* cls_w2   = (const float*)d_in[27];
    const float* cls_b2   = (const float*)d_in[28];
    const float* cls_w3   = (const float*)d_in[29];
    const float* cls_b3   = (const float*)d_in[30];

    float* ws   = (float*)d_ws;
    float* xn   = ws + OFF_XN;
    float* f1   = ws + OFF_F1;
    float* comb = ws + OFF_COMB;
    float* p    = ws + OFF_P;
    float* zx   = ws + OFF_ZX;
    float* xbc  = ws + OFF_XBC;
    float* Sbuf = ws + OFF_S;
    float* dtb  = ws + OFF_DT;
    float* chkT = ws + OFF_CT;
    float* convpart = ws + OFF_S;
    float* c1h  = ws + OFF_XBC;
    float* c2h  = ws + OFF_XBC + 691488;
    float* pr   = ws + OFF_XN;
    float* ybuf = ws + OFF_F1;
    float* mo   = ws + OFF_COMB;
    float* cls0 = ws + OFF_XN;
    float* cls1 = ws + OFF_P;
    float* cls2 = ws + OFF_COMB + 2691200;

    // 1. pre-LN
    ln_kernel<0><<<HW, 256, 0, stream>>>(x, ln_pre_g, ln_pre_b, xn, NBANDS);
    // 2-3. feature MLP (f -> comb[:, :128], ldc=192)
    gemm_mfma<1><<<dim3(4, 165), 256, 0, stream>>>(xn, 200, fe_w1, fe_b1, f1, 256, HW, 256, 200);
    gemm_mfma<1><<<dim3(2, 165), 256, 0, stream>>>(f1, 256, fe_w2, fe_b2, comb, 192, HW, 128, 256);
    // 4. conv1: 200->32, pad 2, ci-split 4
    conv_tiled<200, 32, 2, 25, 2, 8><<<dim3(10, 10, 4), 256, 0, stream>>>(xn, cv_w1, convpart, Hdim, Wdim, CONVH, CONVH);
    conv_reduce<32, 4><<<(CONVHW * 32 + 255) / 256, 256, 0, stream>>>(convpart, cv_b1, c1h, CONVHW);
    // 5. conv2: 32->64, pad 1, ci-split 2
    conv_tiled<32, 64, 1, 16, 1, 16><<<dim3(10, 10, 2), 256, 0, stream>>>(c1h, cv_w2, convpart, CONVH, CONVH, CONVH, CONVH);
    conv_reduce<64, 2><<<(CONVHW * 64 + 255) / 256, 256, 0, stream>>>(convpart, cv_b2, c2h, CONVHW);
    // 6. adaptive pool -> comb[:, 128:192]
    pool_kernel<<<(HW * 64 + 255) / 256, 256, 0, stream>>>(c2h, comb);
    // 7-8. mid projection + LN + GELU
    gemm_mfma<0><<<dim3(2, 165), 256, 0, stream>>>(comb, 192, mp_w, mp_b, pr, 128, HW, 128, 192);
    ln_kernel<1><<<HW, 256, 0, stream>>>(pr, mp_ln_g, mp_ln_b, p, 128);
    // 9. mamba in_proj
    gemm_mfma<0><<<dim3(13, 165), 256, 0, stream>>>(p, 128, m_in_w, (const float*)nullptr, zx, 772, HW, 772, 128);
    // 10. dt softplus
    dt_kernel<<<(HW * 4 + 255) / 256, 256, 0, stream>>>(zx, m_dtb, dtb);
    // 11. depthwise causal conv + silu
    conv1d_kernel<<<dim3(2, HW), 256, 0, stream>>>(zx, m_conv_w, m_conv_b, xbc);
    // 12-14. SSD chunked scan
    ssd_phaseA<<<NCH * 4, 256, 0, stream>>>(xbc, dtb, m_A_log, Sbuf, chkT);
    ssd_phaseB<<<128, 256, 0, stream>>>(Sbuf, chkT);
    ssd_phaseC<<<NCH * 4, 256, 0, stream>>>(xbc, dtb, m_A_log, m_D, Sbuf, ybuf);
    // 15. gated RMSNorm
    gated_rms_kernel<<<HW, 256, 0, stream>>>(ybuf, zx, m_norm_w);
    // 16. out proj
    gemm_mfma<0><<<dim3(2, 165), 256, 0, stream>>>(ybuf, 256, m_out_w, (const float*)nullptr, mo, 128, HW, 128, 256);
    // 17-20. classifier
    ln_kernel<0><<<HW, 256, 0, stream>>>(mo, cls_ln_g, cls_ln_b, cls0, 128);
    gemm_mfma<1><<<dim3(2, 165), 256, 0, stream>>>(cls0, 128, cls_w1, cls_b1, cls1, 128, HW, 128, 128);
    gemm_mfma<1><<<dim3(1, 165), 256, 0, stream>>>(cls1, 128, cls_w2, cls_b2, cls2, 64, HW, 64, 128);
    gemm_mfma<0><<<dim3(1, 165), 256, 0, stream>>>(cls2, 64, cls_w3, cls_b3, (float*)d_out, 17, HW, 17, 64);
}

// Round 4
// 608.212 us; speedup vs baseline: 3.0743x; 1.1662x over previous
//
#include <hip/hip_runtime.h>
#include <math.h>

#define HW 21025        // 145*145
#define Hdim 145
#define Wdim 145
#define NBANDS 200
#define CONVH 147
#define CONVHW 21609    // 147*147
#define QC 64
#define NCH 329         // ceil(21025/64)
#define DTP 21056       // padded L for transposed dt
#define SP 72           // short stride for [.][64-k] MFMA tiles (144B rows, 16B aligned)

typedef __attribute__((ext_vector_type(4))) float fv4;
typedef __attribute__((ext_vector_type(8))) short short8;
typedef unsigned short ushortT;

// ---------------- workspace layout (float offsets) ----------------
#define OFF_XN   ((size_t)0)           // 4,205,000  xn; later pr, cls0
#define OFF_F1   ((size_t)4205000)     // 5,382,400  f1; later y (L x 256)
#define OFF_COMB ((size_t)9587400)     // 4,036,800  comb L x 192; later mo + cls2
#define OFF_P    ((size_t)13624200)    // 2,691,200  p; later cls1
#define OFF_ZX   ((size_t)16315400)    // 16,231,300 zxbcdt L x 772
#define OFF_XBC  ((size_t)32546700)    // 10,764,800 c1h+c2h first, then xbc L x 512
#define OFF_S    ((size_t)43311500)    // 10,780,672 convpart first, then S^T
#define OFF_DT   ((size_t)54092172)    // 84,224 (dt transposed [4][DTP])
#define OFF_CT   ((size_t)54176396)    // 1,316

__device__ __forceinline__ float gelu_f(float x){
    return 0.5f * x * (1.0f + erff(x * 0.70710678118654752440f));
}
__device__ __forceinline__ float silu_f(float x){
    return x / (1.0f + expf(-x));
}

// split f32 -> (hi, lo) bf16 pair; hi = truncate, lo = truncate(x - hi)
__device__ __forceinline__ void bf16_split(float x, unsigned short& hs, unsigned short& ls){
    unsigned u = __float_as_uint(x);
    hs = (unsigned short)(u >> 16);
    float hif = __uint_as_float(u & 0xFFFF0000u);
    float lof = x - hif;
    ls = (unsigned short)(__float_as_uint(lof) >> 16);
}
__device__ __forceinline__ unsigned pack2(unsigned short a, unsigned short b){
    return (unsigned)a | ((unsigned)b << 16);
}

// ---------------- LayerNorm (+ optional GELU) ----------------
template<int ACT>
__global__ void ln_kernel(const float* __restrict__ in, const float* __restrict__ g,
                          const float* __restrict__ b, float* __restrict__ out, int D){
    int row = blockIdx.x, tid = threadIdx.x;
    const float* r = in + (size_t)row * D;
    float s = 0.f, s2 = 0.f;
    for (int i = tid; i < D; i += 256){ float v = r[i]; s += v; s2 += v*v; }
    __shared__ float r1[4], r2[4];
    #pragma unroll
    for (int o = 32; o > 0; o >>= 1){ s += __shfl_down(s, o); s2 += __shfl_down(s2, o); }
    if ((tid & 63) == 0){ r1[tid >> 6] = s; r2[tid >> 6] = s2; }
    __syncthreads();
    float S = r1[0] + r1[1] + r1[2] + r1[3];
    float S2 = r2[0] + r2[1] + r2[2] + r2[3];
    float mean = S / (float)D;
    float var = S2 / (float)D - mean * mean;
    float rs = rsqrtf(fmaxf(var, 0.f) + 1e-5f);
    float* o_ = out + (size_t)row * D;
    for (int i = tid; i < D; i += 256){
        float v = (r[i] - mean) * rs * g[i] + b[i];
        if (ACT == 1) v = gelu_f(v);
        o_[i] = v;
    }
}

// ---------------- split-bf16 MFMA GEMM: C = act(A@B + bias) ----------------
template<int ACT>
__global__ __launch_bounds__(256) void gemm_mfma(const float* __restrict__ A, int lda,
                                                 const float* __restrict__ B,
                                                 const float* __restrict__ bias,
                                                 float* __restrict__ C, int ldc,
                                                 int M, int N, int K){
    const int SA = 40;
    __shared__ __align__(16) unsigned short Ah[128 * SA], Al[128 * SA];
    __shared__ __align__(16) unsigned short Bh[64 * SA],  Bl[64 * SA];
    int tid = threadIdx.x;
    int lane = tid & 63, wid = tid >> 6;
    int wy = wid >> 1, wx = wid & 1;
    int bm = blockIdx.y * 128, bn = blockIdx.x * 64;
    int l15 = lane & 15, g = lane >> 4;

    fv4 acc[4][2];
    #pragma unroll
    for (int i = 0; i < 4; i++)
        #pragma unroll
        for (int j = 0; j < 2; j++) acc[i][j] = (fv4){0.f,0.f,0.f,0.f};

    int am = tid >> 1;
    int aq = (tid & 1) * 4;
    bool arow_ok = (bm + am) < M;
    int bn_t = tid & 63;
    int bk8 = (tid >> 6) * 8;
    bool bcol_ok = (bn + bn_t) < N;

    int nK = (K + 31) / 32;
    for (int ks = 0; ks < nK; ks++){
        int k0 = ks * 32;
        const float* Ap = A + (size_t)(bm + am) * lda + k0;
        #pragma unroll
        for (int f = 0; f < 4; f++){
            int kq = aq + f;
            fv4 v = (fv4){0.f,0.f,0.f,0.f};
            if (arow_ok && (k0 + kq * 4 + 4) <= K)
                v = *reinterpret_cast<const fv4*>(Ap + kq * 4);
            unsigned short hs[4], ls[4];
            #pragma unroll
            for (int j = 0; j < 4; j++) bf16_split(v[j], hs[j], ls[j]);
            unsigned off = am * SA + kq * 4;
            *reinterpret_cast<uint2*>(&Ah[off]) = make_uint2(pack2(hs[0],hs[1]), pack2(hs[2],hs[3]));
            *reinterpret_cast<uint2*>(&Al[off]) = make_uint2(pack2(ls[0],ls[1]), pack2(ls[2],ls[3]));
        }
        {
            unsigned short hs[8], ls[8];
            #pragma unroll
            for (int j = 0; j < 8; j++){
                int kk = k0 + bk8 + j;
                float v = (bcol_ok && kk < K) ? B[(size_t)kk * N + bn + bn_t] : 0.f;
                bf16_split(v, hs[j], ls[j]);
            }
            unsigned off = bn_t * SA + bk8;
            *reinterpret_cast<uint4*>(&Bh[off]) = make_uint4(pack2(hs[0],hs[1]), pack2(hs[2],hs[3]),
                                                             pack2(hs[4],hs[5]), pack2(hs[6],hs[7]));
            *reinterpret_cast<uint4*>(&Bl[off]) = make_uint4(pack2(ls[0],ls[1]), pack2(ls[2],ls[3]),
                                                             pack2(ls[4],ls[5]), pack2(ls[6],ls[7]));
        }
        __syncthreads();
        short8 afh[4], afl[4], bfh[2], bfl[2];
        #pragma unroll
        for (int mi = 0; mi < 4; mi++){
            unsigned off = (wy * 64 + mi * 16 + l15) * SA + g * 8;
            afh[mi] = *reinterpret_cast<const short8*>(&Ah[off]);
            afl[mi] = *reinterpret_cast<const short8*>(&Al[off]);
        }
        #pragma unroll
        for (int ni = 0; ni < 2; ni++){
            unsigned off = (wx * 32 + ni * 16 + l15) * SA + g * 8;
            bfh[ni] = *reinterpret_cast<const short8*>(&Bh[off]);
            bfl[ni] = *reinterpret_cast<const short8*>(&Bl[off]);
        }
        #pragma unroll
        for (int mi = 0; mi < 4; mi++)
            #pragma unroll
            for (int ni = 0; ni < 2; ni++){
                acc[mi][ni] = __builtin_amdgcn_mfma_f32_16x16x32_bf16(afh[mi], bfh[ni], acc[mi][ni], 0, 0, 0);
                acc[mi][ni] = __builtin_amdgcn_mfma_f32_16x16x32_bf16(afh[mi], bfl[ni], acc[mi][ni], 0, 0, 0);
                acc[mi][ni] = __builtin_amdgcn_mfma_f32_16x16x32_bf16(afl[mi], bfh[ni], acc[mi][ni], 0, 0, 0);
            }
        __syncthreads();
    }
    #pragma unroll
    for (int mi = 0; mi < 4; mi++){
        #pragma unroll
        for (int ni = 0; ni < 2; ni++){
            int cc = bn + wx * 32 + ni * 16 + l15;
            if (cc >= N) continue;
            float bv = bias ? bias[cc] : 0.f;
            #pragma unroll
            for (int j = 0; j < 4; j++){
                int rr = bm + wy * 64 + mi * 16 + g * 4 + j;
                if (rr >= M) continue;
                float v = acc[mi][ni][j] + bv;
                if (ACT == 1) v = gelu_f(v);
                C[(size_t)rr * ldc + cc] = v;
            }
        }
    }
}

// ---------------- tiled direct conv 3x3, HWC in / HWC out partials --------------
template<int IC, int OC, int PAD, int CICHUNK, int NCHUNK, int TN>
__global__ __launch_bounds__(256) void conv_tiled(const float* __restrict__ in,
                                                  const float* __restrict__ w,
                                                  float* __restrict__ part,
                                                  int inH, int inW, int outH, int outW){
    const int XST = (CICHUNK % 2 == 0) ? CICHUNK + 1 : CICHUNK;
    __shared__ float xs[324 * XST];
    __shared__ __align__(16) float ws[CICHUNK * 9 * OC];
    int tid = threadIdx.x;
    int q = tid & 63, cg = tid >> 6;
    int qx = q & 7, qy = q >> 3;
    int X0 = blockIdx.x * 16, Y0 = blockIdx.y * 16;
    int lx0 = qx * 2, ly0 = qy * 2;
    int ch0 = cg * TN;
    int ci0 = blockIdx.z * (CICHUNK * NCHUNK);
    int outHW = outH * outW;

    float acc[2][2][TN];
    #pragma unroll
    for (int a = 0; a < 2; a++)
        #pragma unroll
        for (int b = 0; b < 2; b++)
            #pragma unroll
            for (int j = 0; j < TN; j++) acc[a][b][j] = 0.f;

    for (int ch = 0; ch < NCHUNK; ch++){
        int cib = ci0 + ch * CICHUNK;
        for (int e = tid; e < 324 * CICHUNK; e += 256){
            int ci = e % CICHUNK, rest = e / CICHUNK;
            int xx = rest % 18, yy = rest / 18;
            int iy = Y0 - PAD + yy, ix = X0 - PAD + xx;
            float v = 0.f;
            if ((unsigned)iy < (unsigned)inH && (unsigned)ix < (unsigned)inW)
                v = in[((size_t)iy * inW + ix) * IC + cib + ci];
            xs[(yy * 18 + xx) * XST + ci] = v;
        }
        for (int e = tid; e < CICHUNK * 9 * OC; e += 256){
            int o = e % OC, rest = e / OC;
            int tap = rest % 9, ci = rest / 9;
            ws[(ci * 9 + tap) * OC + o] = w[((size_t)o * IC + cib + ci) * 9 + tap];
        }
        __syncthreads();
        for (int ci = 0; ci < CICHUNK; ci++){
            float xv[4][4];
            #pragma unroll
            for (int r = 0; r < 4; r++)
                #pragma unroll
                for (int c = 0; c < 4; c++)
                    xv[r][c] = xs[((ly0 + r) * 18 + (lx0 + c)) * XST + ci];
            #pragma unroll
            for (int ky = 0; ky < 3; ky++)
                #pragma unroll
                for (int kx = 0; kx < 3; kx++){
                    const float* wrow = &ws[(ci * 9 + ky * 3 + kx) * OC + ch0];
                    float wr[TN];
                    #pragma unroll
                    for (int j = 0; j < TN; j += 4)
                        *reinterpret_cast<fv4*>(&wr[j]) = *reinterpret_cast<const fv4*>(&wrow[j]);
                    #pragma unroll
                    for (int j = 0; j < TN; j++){
                        acc[0][0][j] += xv[ky][kx]     * wr[j];
                        acc[0][1][j] += xv[ky][kx + 1] * wr[j];
                        acc[1][0][j] += xv[ky + 1][kx]     * wr[j];
                        acc[1][1][j] += xv[ky + 1][kx + 1] * wr[j];
                    }
                }
        }
        __syncthreads();
    }
    #pragma unroll
    for (int a = 0; a < 2; a++){
        int oy = Y0 + ly0 + a;
        if (oy >= outH) continue;
        #pragma unroll
        for (int b = 0; b < 2; b++){
            int ox = X0 + lx0 + b;
            if (ox >= outW) continue;
            size_t base = ((size_t)blockIdx.z * outHW + (size_t)oy * outW + ox) * OC + ch0;
            #pragma unroll
            for (int j = 0; j < TN; j += 4)
                *reinterpret_cast<fv4*>(&part[base + j]) = *reinterpret_cast<const fv4*>(&acc[a][b][j]);
        }
    }
}

template<int OC, int NSPLIT>
__global__ void conv_reduce(const float* __restrict__ part, const float* __restrict__ bias,
                            float* __restrict__ out, int outHW){
    int idx = blockIdx.x * 256 + threadIdx.x;
    if (idx >= outHW * OC) return;
    int o = idx & (OC - 1);
    float s = bias[o];
    #pragma unroll
    for (int z = 0; z < NSPLIT; z++) s += part[(size_t)z * outHW * OC + idx];
    out[idx] = gelu_f(s);
}

// ---------------- adaptive pool HWC into comb[:,128:] ----------------
__global__ void pool_kernel(const float* __restrict__ c2, float* __restrict__ comb){
    int idx = blockIdx.x * 256 + threadIdx.x;
    if (idx >= HW * 64) return;
    int o = idx & 63;
    int pix = idx >> 6;
    int xo = pix % Wdim, yo = pix / Wdim;
    int ys = yo * CONVH / Hdim, ye = ((yo + 1) * CONVH + Hdim - 1) / Hdim;
    int xs = xo * CONVH / Wdim, xe = ((xo + 1) * CONVH + Wdim - 1) / Wdim;
    float s = 0.f;
    for (int yy = ys; yy < ye; yy++)
        for (int xx = xs; xx < xe; xx++)
            s += c2[((size_t)yy * CONVH + xx) * 64 + o];
    comb[(size_t)pix * 192 + 128 + o] = s / (float)((ye - ys) * (xe - xs));
}

// ---------------- dt = softplus(raw + bias), transposed out [h][t] ----------------
__global__ void dt_kernel(const float* __restrict__ zx, const float* __restrict__ dt_bias,
                          float* __restrict__ dtbT){
    int t = blockIdx.x * 256 + threadIdx.x;
    int h = blockIdx.y;
    if (t >= HW) return;
    float v = zx[(size_t)t * 772 + 768 + h] + dt_bias[h];
    dtbT[h * DTP + t] = (v > 20.f) ? v : log1pf(expf(v));
}

// ---------------- depthwise causal conv1d (width 4) + silu, LDS-tiled ----------------
__global__ __launch_bounds__(256) void conv1d_tiled(const float* __restrict__ zx,
                                                    const float* __restrict__ w,
                                                    const float* __restrict__ b,
                                                    float* __restrict__ xbc){
    __shared__ float xs[67 * 128];
    __shared__ float wc[4 * 128];
    __shared__ float bc[128];
    int t0 = blockIdx.y * 64;
    int c0 = blockIdx.x * 128;
    int tid = threadIdx.x;
    for (int e = tid; e < 67 * 128; e += 256){
        int rr = e >> 7, cc = e & 127;
        int t = t0 - 3 + rr;
        xs[e] = (t >= 0 && t < HW) ? zx[(size_t)t * 772 + 256 + c0 + cc] : 0.f;
    }
    if (tid < 128){
        bc[tid] = b[c0 + tid];
        #pragma unroll
        for (int k = 0; k < 4; k++) wc[k * 128 + tid] = w[(c0 + tid) * 4 + k];
    }
    __syncthreads();
    for (int e = tid; e < 64 * 128; e += 256){
        int tt = e >> 7, cc = e & 127;
        if (t0 + tt >= HW) continue;
        float acc = bc[cc];
        #pragma unroll
        for (int k = 0; k < 4; k++) acc += xs[(tt + k) * 128 + cc] * wc[k * 128 + cc];
        xbc[(size_t)(t0 + tt) * 512 + c0 + cc] = silu_f(acc);
    }
}

// ---------------- chunk cumsum (wave 0) ----------------
__device__ __forceinline__ void chunk_cumsum_t(const float* __restrict__ dtbT, int t0, int Q,
                                               int h, const float* __restrict__ A_log,
                                               float* cum, float* dth){
    int tid = threadIdx.x;
    if (tid < 64){
        float d = (tid < Q) ? dtbT[h * DTP + t0 + tid] : 0.f;
        dth[tid] = d;
        float A = -expf(A_log[h]);
        float a = d * A;
        #pragma unroll
        for (int off = 1; off < 64; off <<= 1){
            float u = __shfl_up(a, off);
            if (tid >= off) a += u;
        }
        cum[tid] = a;
    }
    __syncthreads();
}

// ---------------- SSD phase A (MFMA): S^T[p][n] = sum_s (X w)[s][p] B[s][n] ----------
__global__ __launch_bounds__(256) void ssd_phaseA(const float* __restrict__ xbc,
                                                  const float* __restrict__ dtbT,
                                                  const float* __restrict__ A_log,
                                                  float* __restrict__ S,
                                                  float* __restrict__ chunkT){
    __shared__ __align__(16) unsigned short BTh[128 * SP], BTl[128 * SP]; // B^T [n][s]
    __shared__ __align__(16) unsigned short XTh[64 * SP],  XTl[64 * SP];  // (Xw)^T [p][s]
    __shared__ float cum[64], dth[64], wln[64];
    int bid = blockIdx.x, c = bid >> 2, h = bid & 3;
    int t0 = c * QC, Q = min(QC, HW - t0);
    int tid = threadIdx.x;
    chunk_cumsum_t(dtbT, t0, Q, h, A_log, cum, dth);
    float T = cum[Q - 1];
    if (tid == 0) chunkT[bid] = T;
    if (tid < 64) wln[tid] = (tid < Q) ? __expf(T - cum[tid]) * dth[tid] : 0.f;
    __syncthreads();
    // stage B^T (transposed, split)
    for (int e2 = tid; e2 < 4096; e2 += 256){
        int nn = e2 & 127, sp = e2 >> 7;
        int s0 = 2 * sp;
        float v0 = (s0 < Q)     ? xbc[(size_t)(t0 + s0) * 512 + 256 + nn] : 0.f;
        float v1 = (s0 + 1 < Q) ? xbc[(size_t)(t0 + s0 + 1) * 512 + 256 + nn] : 0.f;
        unsigned short h0, l0, h1, l1;
        bf16_split(v0, h0, l0); bf16_split(v1, h1, l1);
        *reinterpret_cast<unsigned*>(&BTh[nn * SP + s0]) = pack2(h0, h1);
        *reinterpret_cast<unsigned*>(&BTl[nn * SP + s0]) = pack2(l0, l1);
    }
    // stage (Xw)^T
    for (int e2 = tid; e2 < 2048; e2 += 256){
        int pp = e2 & 63, sp = e2 >> 6;
        int s0 = 2 * sp;
        float v0 = (s0 < Q)     ? xbc[(size_t)(t0 + s0) * 512 + h * 64 + pp] * wln[s0] : 0.f;
        float v1 = (s0 + 1 < Q) ? xbc[(size_t)(t0 + s0 + 1) * 512 + h * 64 + pp] * wln[s0 + 1] : 0.f;
        unsigned short h0, l0, h1, l1;
        bf16_split(v0, h0, l0); bf16_split(v1, h1, l1);
        *reinterpret_cast<unsigned*>(&XTh[pp * SP + s0]) = pack2(h0, h1);
        *reinterpret_cast<unsigned*>(&XTl[pp * SP + s0]) = pack2(l0, l1);
    }
    __syncthreads();
    int lane = tid & 63, wid = tid >> 6;
    int wy = wid >> 1, wx = wid & 1;
    int l15 = lane & 15, g = lane >> 4;
    fv4 acc[2][4];
    #pragma unroll
    for (int mi = 0; mi < 2; mi++)
        #pragma unroll
        for (int ni = 0; ni < 4; ni++) acc[mi][ni] = (fv4){0.f,0.f,0.f,0.f};
    #pragma unroll
    for (int ks = 0; ks < 2; ks++){
        short8 ah[2], al[2], bh_[4], bl_[4];
        #pragma unroll
        for (int mi = 0; mi < 2; mi++){
            unsigned off = (wy * 32 + mi * 16 + l15) * SP + ks * 32 + g * 8;
            ah[mi] = *reinterpret_cast<const short8*>(&XTh[off]);
            al[mi] = *reinterpret_cast<const short8*>(&XTl[off]);
        }
        #pragma unroll
        for (int ni = 0; ni < 4; ni++){
            unsigned off = (wx * 64 + ni * 16 + l15) * SP + ks * 32 + g * 8;
            bh_[ni] = *reinterpret_cast<const short8*>(&BTh[off]);
            bl_[ni] = *reinterpret_cast<const short8*>(&BTl[off]);
        }
        #pragma unroll
        for (int mi = 0; mi < 2; mi++)
            #pragma unroll
            for (int ni = 0; ni < 4; ni++){
                acc[mi][ni] = __builtin_amdgcn_mfma_f32_16x16x32_bf16(ah[mi], bh_[ni], acc[mi][ni], 0, 0, 0);
                acc[mi][ni] = __builtin_amdgcn_mfma_f32_16x16x32_bf16(ah[mi], bl_[ni], acc[mi][ni], 0, 0, 0);
                acc[mi][ni] = __builtin_amdgcn_mfma_f32_16x16x32_bf16(al[mi], bh_[ni], acc[mi][ni], 0, 0, 0);
            }
    }
    size_t sb = (size_t)bid * 8192;
    #pragma unroll
    for (int mi = 0; mi < 2; mi++)
        #pragma unroll
        for (int ni = 0; ni < 4; ni++)
            #pragma unroll
            for (int j = 0; j < 4; j++){
                int p = wy * 32 + mi * 16 + g * 4 + j;
                int n = wx * 64 + ni * 16 + l15;
                S[sb + p * 128 + n] = acc[mi][ni][j];
            }
}

// ---------------- SSD phase B: in-place prefix over chunks (pipelined) ------------
__global__ __launch_bounds__(256) void ssd_phaseB(float* __restrict__ S,
                                                  const float* __restrict__ chunkT){
    __shared__ float e[NCH];
    int tid = threadIdx.x;
    int idx = blockIdx.x * 256 + tid;
    int h = idx >> 13, pn = idx & 8191;
    for (int c = tid; c < NCH; c += 256) e[c] = __expf(chunkT[c * 4 + h]);
    __syncthreads();
    #define LDS_(cc) S[((size_t)((cc) * 4 + h)) * 8192 + pn]
    float b0 = LDS_(0), b1 = LDS_(1), b2 = LDS_(2), b3 = LDS_(3);
    float s = 0.f;
    int c = 0;
    for (; c + 8 <= NCH; c += 4){
        float n0 = LDS_(c + 4), n1 = LDS_(c + 5), n2 = LDS_(c + 6), n3 = LDS_(c + 7);
        LDS_(c) = s;     s = fmaf(s, e[c],     b0);
        LDS_(c + 1) = s; s = fmaf(s, e[c + 1], b1);
        LDS_(c + 2) = s; s = fmaf(s, e[c + 2], b2);
        LDS_(c + 3) = s; s = fmaf(s, e[c + 3], b3);
        b0 = n0; b1 = n1; b2 = n2; b3 = n3;
    }
    for (; c < NCH; c++){
        float nx = (c + 4 < NCH) ? LDS_(c + 4) : 0.f;
        float loc = b0; b0 = b1; b1 = b2; b2 = b3; b3 = nx;
        LDS_(c) = s;
        s = fmaf(s, e[c], loc);
    }
    #undef LDS_
}

// ---------------- SSD phase C (MFMA) ----------------
__global__ __launch_bounds__(256) void ssd_phaseC(const float* __restrict__ xbc,
                                                  const float* __restrict__ dtbT,
                                                  const float* __restrict__ A_log,
                                                  const float* __restrict__ Dvec,
                                                  const float* __restrict__ S,
                                                  float* __restrict__ y){
    __shared__ __align__(16) unsigned short Ch_[64 * SP], Cl_[64 * SP]; // C-chunk [t][nc]; later X^T [p][s]
    __shared__ __align__(16) unsigned short Bh_[64 * SP], Bl_[64 * SP]; // B-chunk [s][nc]; later P [t][s]
    __shared__ __align__(16) unsigned short Sh_[64 * SP], Sl_[64 * SP]; // S^T-chunk [p][nc]
    __shared__ float cum[64], dth[64];
    int bid = blockIdx.x, c = bid >> 2, h = bid & 3;
    int t0 = c * QC, Q = min(QC, HW - t0);
    int tid = threadIdx.x;
    chunk_cumsum_t(dtbT, t0, Q, h, A_log, cum, dth);
    int lane = tid & 63, wid = tid >> 6;
    int wy = wid >> 1, wx = wid & 1;
    int l15 = lane & 15, g = lane >> 4;
    size_t sb = (size_t)bid * 8192;

    fv4 accG[2][2], accA[2][2];
    #pragma unroll
    for (int mi = 0; mi < 2; mi++)
        #pragma unroll
        for (int ni = 0; ni < 2; ni++){ accG[mi][ni] = (fv4){0.f,0.f,0.f,0.f}; accA[mi][ni] = (fv4){0.f,0.f,0.f,0.f}; }

    #pragma unroll
    for (int ks = 0; ks < 2; ks++){
        int n0 = ks * 64;
        for (int e2 = tid; e2 < 2048; e2 += 256){
            int rr = e2 >> 5, n2 = (e2 & 31) * 2;
            bool ok = rr < Q;
            float c0 = ok ? xbc[(size_t)(t0 + rr) * 512 + 384 + n0 + n2]     : 0.f;
            float c1 = ok ? xbc[(size_t)(t0 + rr) * 512 + 384 + n0 + n2 + 1] : 0.f;
            float b0 = ok ? xbc[(size_t)(t0 + rr) * 512 + 256 + n0 + n2]     : 0.f;
            float b1 = ok ? xbc[(size_t)(t0 + rr) * 512 + 256 + n0 + n2 + 1] : 0.f;
            float s0 = S[sb + rr * 128 + n0 + n2];
            float s1 = S[sb + rr * 128 + n0 + n2 + 1];
            unsigned short xh0, xl0, xh1, xl1;
            bf16_split(c0, xh0, xl0); bf16_split(c1, xh1, xl1);
            *reinterpret_cast<unsigned*>(&Ch_[rr * SP + n2]) = pack2(xh0, xh1);
            *reinterpret_cast<unsigned*>(&Cl_[rr * SP + n2]) = pack2(xl0, xl1);
            bf16_split(b0, xh0, xl0); bf16_split(b1, xh1, xl1);
            *reinterpret_cast<unsigned*>(&Bh_[rr * SP + n2]) = pack2(xh0, xh1);
            *reinterpret_cast<unsigned*>(&Bl_[rr * SP + n2]) = pack2(xl0, xl1);
            bf16_split(s0, xh0, xl0); bf16_split(s1, xh1, xl1);
            *reinterpret_cast<unsigned*>(&Sh_[rr * SP + n2]) = pack2(xh0, xh1);
            *reinterpret_cast<unsigned*>(&Sl_[rr * SP + n2]) = pack2(xl0, xl1);
        }
        __syncthreads();
        #pragma unroll
        for (int kk = 0; kk < 2; kk++){
            short8 ah[2], al[2], gh[2], gl[2], sh[2], sl[2];
            #pragma unroll
            for (int mi = 0; mi < 2; mi++){
                unsigned off = (wy * 32 + mi * 16 + l15) * SP + kk * 32 + g * 8;
                ah[mi] = *reinterpret_cast<const short8*>(&Ch_[off]);
                al[mi] = *reinterpret_cast<const short8*>(&Cl_[off]);
            }
            #pragma unroll
            for (int ni = 0; ni < 2; ni++){
                unsigned off = (wx * 32 + ni * 16 + l15) * SP + kk * 32 + g * 8;
                gh[ni] = *reinterpret_cast<const short8*>(&Bh_[off]);
                gl[ni] = *reinterpret_cast<const short8*>(&Bl_[off]);
                sh[ni] = *reinterpret_cast<const short8*>(&Sh_[off]);
                sl[ni] = *reinterpret_cast<const short8*>(&Sl_[off]);
            }
            #pragma unroll
            for (int mi = 0; mi < 2; mi++)
                #pragma unroll
                for (int ni = 0; ni < 2; ni++){
                    accG[mi][ni] = __builtin_amdgcn_mfma_f32_16x16x32_bf16(ah[mi], gh[ni], accG[mi][ni], 0, 0, 0);
                    accG[mi][ni] = __builtin_amdgcn_mfma_f32_16x16x32_bf16(ah[mi], gl[ni], accG[mi][ni], 0, 0, 0);
                    accG[mi][ni] = __builtin_amdgcn_mfma_f32_16x16x32_bf16(al[mi], gh[ni], accG[mi][ni], 0, 0, 0);
                    accA[mi][ni] = __builtin_amdgcn_mfma_f32_16x16x32_bf16(ah[mi], sh[ni], accA[mi][ni], 0, 0, 0);
                    accA[mi][ni] = __builtin_amdgcn_mfma_f32_16x16x32_bf16(ah[mi], sl[ni], accA[mi][ni], 0, 0, 0);
                    accA[mi][ni] = __builtin_amdgcn_mfma_f32_16x16x32_bf16(al[mi], sh[ni], accA[mi][ni], 0, 0, 0);
                }
        }
        __syncthreads();
    }
    // P = mask(G) * exp(cum_t - cum_s) * dt_s  -> split into Bh_/Bl_ ([t][s])
    #pragma unroll
    for (int mi = 0; mi < 2; mi++)
        #pragma unroll
        for (int ni = 0; ni < 2; ni++)
            #pragma unroll
            for (int j = 0; j < 4; j++){
                int t = wy * 32 + mi * 16 + g * 4 + j;
                int s = wx * 32 + ni * 16 + l15;
                float pv = 0.f;
                if (s <= t && s < Q)
                    pv = accG[mi][ni][j] * __expf(cum[t] - cum[s]) * dth[s];
                unsigned short hs, ls;
                bf16_split(pv, hs, ls);
                Bh_[t * SP + s] = hs;
                Bl_[t * SP + s] = ls;
            }
    // stage X^T [p][s] into Ch_/Cl_
    for (int e2 = tid; e2 < 2048; e2 += 256){
        int pp = e2 & 63, sp = e2 >> 6;
        int s0 = 2 * sp;
        float v0 = (s0 < Q)     ? xbc[(size_t)(t0 + s0) * 512 + h * 64 + pp] : 0.f;
        float v1 = (s0 + 1 < Q) ? xbc[(size_t)(t0 + s0 + 1) * 512 + h * 64 + pp] : 0.f;
        unsigned short h0, l0, h1, l1;
        bf16_split(v0, h0, l0); bf16_split(v1, h1, l1);
        *reinterpret_cast<unsigned*>(&Ch_[pp * SP + s0]) = pack2(h0, h1);
        *reinterpret_cast<unsigned*>(&Cl_[pp * SP + s0]) = pack2(l0, l1);
    }
    __syncthreads();
    // Y = exp(cum_t)*accA  +  P @ X
    fv4 accY[2][2];
    #pragma unroll
    for (int mi = 0; mi < 2; mi++)
        #pragma unroll
        for (int ni = 0; ni < 2; ni++)
            #pragma unroll
            for (int j = 0; j < 4; j++){
                int t = wy * 32 + mi * 16 + g * 4 + j;
                accY[mi][ni][j] = __expf(cum[t]) * accA[mi][ni][j];
            }
    #pragma unroll
    for (int kk = 0; kk < 2; kk++){
        short8 ph[2], pl[2], xh[2], xl[2];
        #pragma unroll
        for (int mi = 0; mi < 2; mi++){
            unsigned off = (wy * 32 + mi * 16 + l15) * SP + kk * 32 + g * 8;
            ph[mi] = *reinterpret_cast<const short8*>(&Bh_[off]);
            pl[mi] = *reinterpret_cast<const short8*>(&Bl_[off]);
        }
        #pragma unroll
        for (int ni = 0; ni < 2; ni++){
            unsigned off = (wx * 32 + ni * 16 + l15) * SP + kk * 32 + g * 8;
            xh[ni] = *reinterpret_cast<const short8*>(&Ch_[off]);
            xl[ni] = *reinterpret_cast<const short8*>(&Cl_[off]);
        }
        #pragma unroll
        for (int mi = 0; mi < 2; mi++)
            #pragma unroll
            for (int ni = 0; ni < 2; ni++){
                accY[mi][ni] = __builtin_amdgcn_mfma_f32_16x16x32_bf16(ph[mi], xh[ni], accY[mi][ni], 0, 0, 0);
                accY[mi][ni] = __builtin_amdgcn_mfma_f32_16x16x32_bf16(ph[mi], xl[ni], accY[mi][ni], 0, 0, 0);
                accY[mi][ni] = __builtin_amdgcn_mfma_f32_16x16x32_bf16(pl[mi], xh[ni], accY[mi][ni], 0, 0, 0);
            }
    }
    float Dh = Dvec[h];
    #pragma unroll
    for (int mi = 0; mi < 2; mi++)
        #pragma unroll
        for (int ni = 0; ni < 2; ni++)
            #pragma unroll
            for (int j = 0; j < 4; j++){
                int t = wy * 32 + mi * 16 + g * 4 + j;
                if (t >= Q) continue;
                int p = wx * 32 + ni * 16 + l15;
                float xv = xbc[(size_t)(t0 + t) * 512 + h * 64 + p];
                y[(size_t)(t0 + t) * 256 + h * 64 + p] = accY[mi][ni][j] + Dh * xv;
            }
}

// ---------------- gated RMSNorm ----------------
__global__ void gated_rms_kernel(float* __restrict__ y, const float* __restrict__ zx,
                                 const float* __restrict__ nw){
    int row = blockIdx.x, tid = threadIdx.x;
    float v = y[(size_t)row * 256 + tid];
    float z = zx[(size_t)row * 772 + tid];
    v *= silu_f(z);
    float s = v * v;
    __shared__ float r1[4];
    #pragma unroll
    for (int o = 32; o > 0; o >>= 1) s += __shfl_down(s, o);
    if ((tid & 63) == 0) r1[tid >> 6] = s;
    __syncthreads();
    float S = r1[0] + r1[1] + r1[2] + r1[3];
    float rs = rsqrtf(S / 256.f + 1e-5f);
    y[(size_t)row * 256 + tid] = v * rs * nw[tid];
}

extern "C" void kernel_launch(void* const* d_in, const int* in_sizes, int n_in,
                              void* d_out, int out_size, void* d_ws, size_t ws_size,
                              hipStream_t stream){
    (void)in_sizes; (void)n_in; (void)out_size; (void)ws_size;
    const float* x        = (const float*)d_in[0];
    const float* ln_pre_g = (const float*)d_in[1];
    const float* ln_pre_b = (const float*)d_in[2];
    const float* fe_w1    = (const float*)d_in[3];
    const float* fe_b1    = (const float*)d_in[4];
    const float* fe_w2    = (const float*)d_in[5];
    const float* fe_b2    = (const float*)d_in[6];
    const float* cv_w1    = (const float*)d_in[7];
    const float* cv_b1    = (const float*)d_in[8];
    const float* cv_w2    = (const float*)d_in[9];
    const float* cv_b2    = (const float*)d_in[10];
    const float* mp_w     = (const float*)d_in[11];
    const float* mp_b     = (const float*)d_in[12];
    const float* mp_ln_g  = (const float*)d_in[13];
    const float* mp_ln_b  = (const float*)d_in[14];
    const float* m_in_w   = (const float*)d_in[15];
    const float* m_conv_w = (const float*)d_in[16];
    const float* m_conv_b = (const float*)d_in[17];
    const float* m_dtb    = (const float*)d_in[18];
    const float* m_A_log  = (const float*)d_in[19];
    const float* m_D      = (const float*)d_in[20];
    const float* m_norm_w = (const float*)d_in[21];
    const float* m_out_w  = (const float*)d_in[22];
    const float* cls_ln_g = (const float*)d_in[23];
    const float* cls_ln_b = (const float*)d_in[24];
    const float* cls_w1   = (const float*)d_in[25];
    const float* cls_b1   = (const float*)d_in[26];
    const float* cls_w2   = (const float*)d_in[27];
    const float* cls_b2   = (const float*)d_in[28];
    const float* cls_w3   = (const float*)d_in[29];
    const float* cls_b3   = (const float*)d_in[30];

    float* ws   = (float*)d_ws;
    float* xn   = ws + OFF_XN;
    float* f1   = ws + OFF_F1;
    float* comb = ws + OFF_COMB;
    float* p    = ws + OFF_P;
    float* zx   = ws + OFF_ZX;
    float* xbc  = ws + OFF_XBC;
    float* Sbuf = ws + OFF_S;
    float* dtbT = ws + OFF_DT;
    float* chkT = ws + OFF_CT;
    float* convpart = ws + OFF_S;
    float* c1h  = ws + OFF_XBC;
    float* c2h  = ws + OFF_XBC + 691488;
    float* pr   = ws + OFF_XN;
    float* ybuf = ws + OFF_F1;
    float* mo   = ws + OFF_COMB;
    float* cls0 = ws + OFF_XN;
    float* cls1 = ws + OFF_P;
    float* cls2 = ws + OFF_COMB + 2691200;

    // 1. pre-LN
    ln_kernel<0><<<HW, 256, 0, stream>>>(x, ln_pre_g, ln_pre_b, xn, NBANDS);
    // 2-3. feature MLP (f -> comb[:, :128], ldc=192)
    gemm_mfma<1><<<dim3(4, 165), 256, 0, stream>>>(xn, 200, fe_w1, fe_b1, f1, 256, HW, 256, 200);
    gemm_mfma<1><<<dim3(2, 165), 256, 0, stream>>>(f1, 256, fe_w2, fe_b2, comb, 192, HW, 128, 256);
    // 4. conv1: 200->32, pad 2, ci-split 4
    conv_tiled<200, 32, 2, 25, 2, 8><<<dim3(10, 10, 4), 256, 0, stream>>>(xn, cv_w1, convpart, Hdim, Wdim, CONVH, CONVH);
    conv_reduce<32, 4><<<(CONVHW * 32 + 255) / 256, 256, 0, stream>>>(convpart, cv_b1, c1h, CONVHW);
    // 5. conv2: 32->64, pad 1, ci-split 2
    conv_tiled<32, 64, 1, 16, 1, 16><<<dim3(10, 10, 2), 256, 0, stream>>>(c1h, cv_w2, convpart, CONVH, CONVH, CONVH, CONVH);
    conv_reduce<64, 2><<<(CONVHW * 64 + 255) / 256, 256, 0, stream>>>(convpart, cv_b2, c2h, CONVHW);
    // 6. adaptive pool -> comb[:, 128:192]
    pool_kernel<<<(HW * 64 + 255) / 256, 256, 0, stream>>>(c2h, comb);
    // 7-8. mid projection + LN + GELU
    gemm_mfma<0><<<dim3(2, 165), 256, 0, stream>>>(comb, 192, mp_w, mp_b, pr, 128, HW, 128, 192);
    ln_kernel<1><<<HW, 256, 0, stream>>>(pr, mp_ln_g, mp_ln_b, p, 128);
    // 9. mamba in_proj
    gemm_mfma<0><<<dim3(13, 165), 256, 0, stream>>>(p, 128, m_in_w, (const float*)nullptr, zx, 772, HW, 772, 128);
    // 10. dt softplus (transposed [h][t])
    dt_kernel<<<dim3((HW + 255) / 256, 4), 256, 0, stream>>>(zx, m_dtb, dtbT);
    // 11. depthwise causal conv + silu (tiled)
    conv1d_tiled<<<dim3(4, NCH), 256, 0, stream>>>(zx, m_conv_w, m_conv_b, xbc);
    // 12-14. SSD chunked scan (MFMA)
    ssd_phaseA<<<NCH * 4, 256, 0, stream>>>(xbc, dtbT, m_A_log, Sbuf, chkT);
    ssd_phaseB<<<128, 256, 0, stream>>>(Sbuf, chkT);
    ssd_phaseC<<<NCH * 4, 256, 0, stream>>>(xbc, dtbT, m_A_log, m_D, Sbuf, ybuf);
    // 15. gated RMSNorm
    gated_rms_kernel<<<HW, 256, 0, stream>>>(ybuf, zx, m_norm_w);
    // 16. out proj
    gemm_mfma<0><<<dim3(2, 165), 256, 0, stream>>>(ybuf, 256, m_out_w, (const float*)nullptr, mo, 128, HW, 128, 256);
    // 17-20. classifier
    ln_kernel<0><<<HW, 256, 0, stream>>>(mo, cls_ln_g, cls_ln_b, cls0, 128);
    gemm_mfma<1><<<dim3(2, 165), 256, 0, stream>>>(cls0, 128, cls_w1, cls_b1, cls1, 128, HW, 128, 128);
    gemm_mfma<1><<<dim3(1, 165), 256, 0, stream>>>(cls1, 128, cls_w2, cls_b2, cls2, 64, HW, 64, 128);
    gemm_mfma<0><<<dim3(1, 165), 256, 0, stream>>>(cls2, 64, cls_w3, cls_b3, (float*)d_out, 17, HW, 17, 64);
}

// Round 5
// 517.555 us; speedup vs baseline: 3.6128x; 1.1752x over previous
//
#include <hip/hip_runtime.h>
#include <math.h>

#define HW 21025        // 145*145
#define Hdim 145
#define Wdim 145
#define NBANDS 200
#define CONVH 147
#define CONVHW 21609    // 147*147
#define QC 64
#define NCH 329         // ceil(21025/64)
#define DTP 21056       // padded L for transposed dt
#define SP 72           // short stride for [.][64-k] MFMA tiles

typedef __attribute__((ext_vector_type(4))) float fv4;
typedef __attribute__((ext_vector_type(8))) short short8;

// ---------------- workspace layout (float offsets) ----------------
#define OFF_XN   ((size_t)0)           // 4,205,000  xn; later pr, cls0
#define OFF_F1   ((size_t)4205000)     // 5,382,400  f1; later y (L x 256)
#define OFF_COMB ((size_t)9587400)     // 4,036,800  comb L x 192; later mo + cls2
#define OFF_P    ((size_t)13624200)    // 2,691,200  p; later cls1
#define OFF_ZX   ((size_t)16315400)    // 16,231,300 zxbcdt L x 772
#define OFF_XBC  ((size_t)32546700)    // 10,764,800 c1h+c2h first, then xbc L x 512
#define OFF_S    ((size_t)43311500)    // 10,780,672 S^T
#define OFF_DT   ((size_t)54092172)    // 84,224 (dt transposed [4][DTP])
#define OFF_CT   ((size_t)54176396)    // 1,316
#define OFF_W    ((size_t)54177712)    // 82,944: packed conv weights (bf16 hi/lo)

__device__ __forceinline__ float gelu_f(float x){
    return 0.5f * x * (1.0f + erff(x * 0.70710678118654752440f));
}
__device__ __forceinline__ float silu_f(float x){
    return x / (1.0f + expf(-x));
}

__device__ __forceinline__ void bf16_split(float x, unsigned short& hs, unsigned short& ls){
    unsigned u = __float_as_uint(x);
    hs = (unsigned short)(u >> 16);
    float hif = __uint_as_float(u & 0xFFFF0000u);
    float lof = x - hif;
    ls = (unsigned short)(__float_as_uint(lof) >> 16);
}
__device__ __forceinline__ unsigned pack2(unsigned short a, unsigned short b){
    return (unsigned)a | ((unsigned)b << 16);
}

// ---------------- LayerNorm (+ optional GELU) ----------------
template<int ACT>
__global__ void ln_kernel(const float* __restrict__ in, const float* __restrict__ g,
                          const float* __restrict__ b, float* __restrict__ out, int D){
    int row = blockIdx.x, tid = threadIdx.x;
    const float* r = in + (size_t)row * D;
    float s = 0.f, s2 = 0.f;
    for (int i = tid; i < D; i += 256){ float v = r[i]; s += v; s2 += v*v; }
    __shared__ float r1[4], r2[4];
    #pragma unroll
    for (int o = 32; o > 0; o >>= 1){ s += __shfl_down(s, o); s2 += __shfl_down(s2, o); }
    if ((tid & 63) == 0){ r1[tid >> 6] = s; r2[tid >> 6] = s2; }
    __syncthreads();
    float S = r1[0] + r1[1] + r1[2] + r1[3];
    float S2 = r2[0] + r2[1] + r2[2] + r2[3];
    float mean = S / (float)D;
    float var = S2 / (float)D - mean * mean;
    float rs = rsqrtf(fmaxf(var, 0.f) + 1e-5f);
    float* o_ = out + (size_t)row * D;
    for (int i = tid; i < D; i += 256){
        float v = (r[i] - mean) * rs * g[i] + b[i];
        if (ACT == 1) v = gelu_f(v);
        o_[i] = v;
    }
}

// ---------------- split-bf16 MFMA GEMM: C = act(A@B + bias) ----------------
template<int ACT>
__global__ __launch_bounds__(256) void gemm_mfma(const float* __restrict__ A, int lda,
                                                 const float* __restrict__ B,
                                                 const float* __restrict__ bias,
                                                 float* __restrict__ C, int ldc,
                                                 int M, int N, int K){
    const int SA = 40;
    __shared__ __align__(16) unsigned short Ah[128 * SA], Al[128 * SA];
    __shared__ __align__(16) unsigned short Bh[64 * SA],  Bl[64 * SA];
    int tid = threadIdx.x;
    int lane = tid & 63, wid = tid >> 6;
    int wy = wid >> 1, wx = wid & 1;
    int bm = blockIdx.y * 128, bn = blockIdx.x * 64;
    int l15 = lane & 15, g = lane >> 4;

    fv4 acc[4][2];
    #pragma unroll
    for (int i = 0; i < 4; i++)
        #pragma unroll
        for (int j = 0; j < 2; j++) acc[i][j] = (fv4){0.f,0.f,0.f,0.f};

    int am = tid >> 1;
    int aq = (tid & 1) * 4;
    bool arow_ok = (bm + am) < M;
    int bn_t = tid & 63;
    int bk8 = (tid >> 6) * 8;
    bool bcol_ok = (bn + bn_t) < N;

    int nK = (K + 31) / 32;
    for (int ks = 0; ks < nK; ks++){
        int k0 = ks * 32;
        const float* Ap = A + (size_t)(bm + am) * lda + k0;
        #pragma unroll
        for (int f = 0; f < 4; f++){
            int kq = aq + f;
            fv4 v = (fv4){0.f,0.f,0.f,0.f};
            if (arow_ok && (k0 + kq * 4 + 4) <= K)
                v = *reinterpret_cast<const fv4*>(Ap + kq * 4);
            unsigned short hs[4], ls[4];
            #pragma unroll
            for (int j = 0; j < 4; j++) bf16_split(v[j], hs[j], ls[j]);
            unsigned off = am * SA + kq * 4;
            *reinterpret_cast<uint2*>(&Ah[off]) = make_uint2(pack2(hs[0],hs[1]), pack2(hs[2],hs[3]));
            *reinterpret_cast<uint2*>(&Al[off]) = make_uint2(pack2(ls[0],ls[1]), pack2(ls[2],ls[3]));
        }
        {
            unsigned short hs[8], ls[8];
            #pragma unroll
            for (int j = 0; j < 8; j++){
                int kk = k0 + bk8 + j;
                float v = (bcol_ok && kk < K) ? B[(size_t)kk * N + bn + bn_t] : 0.f;
                bf16_split(v, hs[j], ls[j]);
            }
            unsigned off = bn_t * SA + bk8;
            *reinterpret_cast<uint4*>(&Bh[off]) = make_uint4(pack2(hs[0],hs[1]), pack2(hs[2],hs[3]),
                                                             pack2(hs[4],hs[5]), pack2(hs[6],hs[7]));
            *reinterpret_cast<uint4*>(&Bl[off]) = make_uint4(pack2(ls[0],ls[1]), pack2(ls[2],ls[3]),
                                                             pack2(ls[4],ls[5]), pack2(ls[6],ls[7]));
        }
        __syncthreads();
        short8 afh[4], afl[4], bfh[2], bfl[2];
        #pragma unroll
        for (int mi = 0; mi < 4; mi++){
            unsigned off = (wy * 64 + mi * 16 + l15) * SA + g * 8;
            afh[mi] = *reinterpret_cast<const short8*>(&Ah[off]);
            afl[mi] = *reinterpret_cast<const short8*>(&Al[off]);
        }
        #pragma unroll
        for (int ni = 0; ni < 2; ni++){
            unsigned off = (wx * 32 + ni * 16 + l15) * SA + g * 8;
            bfh[ni] = *reinterpret_cast<const short8*>(&Bh[off]);
            bfl[ni] = *reinterpret_cast<const short8*>(&Bl[off]);
        }
        #pragma unroll
        for (int mi = 0; mi < 4; mi++)
            #pragma unroll
            for (int ni = 0; ni < 2; ni++){
                acc[mi][ni] = __builtin_amdgcn_mfma_f32_16x16x32_bf16(afh[mi], bfh[ni], acc[mi][ni], 0, 0, 0);
                acc[mi][ni] = __builtin_amdgcn_mfma_f32_16x16x32_bf16(afh[mi], bfl[ni], acc[mi][ni], 0, 0, 0);
                acc[mi][ni] = __builtin_amdgcn_mfma_f32_16x16x32_bf16(afl[mi], bfh[ni], acc[mi][ni], 0, 0, 0);
            }
        __syncthreads();
    }
    #pragma unroll
    for (int mi = 0; mi < 4; mi++){
        #pragma unroll
        for (int ni = 0; ni < 2; ni++){
            int cc = bn + wx * 32 + ni * 16 + l15;
            if (cc >= N) continue;
            float bv = bias ? bias[cc] : 0.f;
            #pragma unroll
            for (int j = 0; j < 4; j++){
                int rr = bm + wy * 64 + mi * 16 + g * 4 + j;
                if (rr >= M) continue;
                float v = acc[mi][ni][j] + bv;
                if (ACT == 1) v = gelu_f(v);
                C[(size_t)rr * ldc + cc] = v;
            }
        }
    }
}

// ---------------- conv weight prepack: [oc][ch*288 + tap*32 + ci] bf16 hi/lo -------
template<int IC, int OC, int NCHUNK>
__global__ void prep_w(const float* __restrict__ w, unsigned short* __restrict__ Wh,
                       unsigned short* __restrict__ Wl){
    const int KP = NCHUNK * 288;
    int idx = blockIdx.x * 256 + threadIdx.x;
    if (idx >= OC * KP) return;
    int o = idx / KP, k = idx % KP;
    int ch = k / 288, rest = k % 288, t = rest / 32, c = rest & 31;
    int ci = ch * 32 + c;
    float v = (ci < IC) ? w[((size_t)o * IC + ci) * 9 + t] : 0.f;
    unsigned short hs, ls;
    bf16_split(v, hs, ls);
    Wh[idx] = hs; Wl[idx] = ls;
}

// ---------------- MFMA direct conv 3x3 (implicit im2col in LDS) -------------------
// block: 64 consecutive out-x in one row y, all OC. waves 2x2 (pix-half, oc-half).
// K-tile = one tap x 32 ci. Weights pre-packed [oc][k] in global (L2).
template<int IC, int OC, int PAD, int NCHUNK, int NFRAG>
__global__ __launch_bounds__(256) void conv_mfma(const float* __restrict__ in,
                                                 int inH, int inW,
                                                 const unsigned short* __restrict__ Wh,
                                                 const unsigned short* __restrict__ Wl,
                                                 const float* __restrict__ bias,
                                                 float* __restrict__ out){
    const int KP = NCHUNK * 288;
    const int CST = 40;                       // short stride per input cell
    __shared__ __align__(16) unsigned short Xh[3 * 68 * CST], Xl[3 * 68 * CST];
    int y = blockIdx.y;
    int x0 = blockIdx.x * 64;
    int tid = threadIdx.x;
    int lane = tid & 63, wid = tid >> 6;
    int wy = wid >> 1, wx = wid & 1;
    int l15 = lane & 15, g = lane >> 4;

    fv4 acc[2][NFRAG];
    #pragma unroll
    for (int mi = 0; mi < 2; mi++)
        #pragma unroll
        for (int ni = 0; ni < NFRAG; ni++) acc[mi][ni] = (fv4){0.f,0.f,0.f,0.f};

    for (int ch = 0; ch < NCHUNK; ch++){
        int ci0 = ch * 32;
        if (ch > 0) __syncthreads();
        // stage 3 rows x 68 cols x 32 ci (fv4-granular), split to bf16 hi/lo
        for (int e = tid; e < 3 * 68 * 8; e += 256){
            int qd = e & 7;
            int c  = (e >> 3) % 68;
            int r  = e / 544;
            int iy = y - PAD + r, ix = x0 - PAD + c;
            fv4 v = (fv4){0.f,0.f,0.f,0.f};
            if ((unsigned)iy < (unsigned)inH && (unsigned)ix < (unsigned)inW &&
                (ci0 + qd * 4 + 4) <= IC)
                v = *reinterpret_cast<const fv4*>(in + ((size_t)iy * inW + ix) * IC + ci0 + qd * 4);
            unsigned short hs[4], ls[4];
            #pragma unroll
            for (int j = 0; j < 4; j++) bf16_split(v[j], hs[j], ls[j]);
            unsigned off = (r * 68 + c) * CST + qd * 4;
            *reinterpret_cast<uint2*>(&Xh[off]) = make_uint2(pack2(hs[0],hs[1]), pack2(hs[2],hs[3]));
            *reinterpret_cast<uint2*>(&Xl[off]) = make_uint2(pack2(ls[0],ls[1]), pack2(ls[2],ls[3]));
        }
        __syncthreads();
        #pragma unroll
        for (int t = 0; t < 9; t++){
            int ky = t / 3, kx = t % 3;
            short8 ah[2], al[2], bh[NFRAG], bl[NFRAG];
            #pragma unroll
            for (int mi = 0; mi < 2; mi++){
                unsigned off = (ky * 68 + wy * 32 + mi * 16 + l15 + kx) * CST + g * 8;
                ah[mi] = *reinterpret_cast<const short8*>(&Xh[off]);
                al[mi] = *reinterpret_cast<const short8*>(&Xl[off]);
            }
            #pragma unroll
            for (int ni = 0; ni < NFRAG; ni++){
                int oc = wx * (16 * NFRAG) + ni * 16 + l15;
                size_t woff = (size_t)oc * KP + ch * 288 + t * 32 + g * 8;
                bh[ni] = *reinterpret_cast<const short8*>(&Wh[woff]);
                bl[ni] = *reinterpret_cast<const short8*>(&Wl[woff]);
            }
            #pragma unroll
            for (int mi = 0; mi < 2; mi++)
                #pragma unroll
                for (int ni = 0; ni < NFRAG; ni++){
                    acc[mi][ni] = __builtin_amdgcn_mfma_f32_16x16x32_bf16(ah[mi], bh[ni], acc[mi][ni], 0, 0, 0);
                    acc[mi][ni] = __builtin_amdgcn_mfma_f32_16x16x32_bf16(ah[mi], bl[ni], acc[mi][ni], 0, 0, 0);
                    acc[mi][ni] = __builtin_amdgcn_mfma_f32_16x16x32_bf16(al[mi], bh[ni], acc[mi][ni], 0, 0, 0);
                }
        }
    }
    // epilogue: pixel m = wy*32 + mi*16 + g*4 + j ; oc = wx*(16*NFRAG) + ni*16 + l15
    #pragma unroll
    for (int mi = 0; mi < 2; mi++)
        #pragma unroll
        for (int ni = 0; ni < NFRAG; ni++){
            int oc = wx * (16 * NFRAG) + ni * 16 + l15;
            float bv = bias[oc];
            #pragma unroll
            for (int j = 0; j < 4; j++){
                int x = x0 + wy * 32 + mi * 16 + g * 4 + j;
                if (x >= CONVH) continue;
                out[((size_t)y * CONVH + x) * OC + oc] = gelu_f(acc[mi][ni][j] + bv);
            }
        }
}

// ---------------- adaptive pool HWC into comb[:,128:] ----------------
__global__ void pool_kernel(const float* __restrict__ c2, float* __restrict__ comb){
    int idx = blockIdx.x * 256 + threadIdx.x;
    if (idx >= HW * 64) return;
    int o = idx & 63;
    int pix = idx >> 6;
    int xo = pix % Wdim, yo = pix / Wdim;
    int ys = yo * CONVH / Hdim, ye = ((yo + 1) * CONVH + Hdim - 1) / Hdim;
    int xs = xo * CONVH / Wdim, xe = ((xo + 1) * CONVH + Wdim - 1) / Wdim;
    float s = 0.f;
    for (int yy = ys; yy < ye; yy++)
        for (int xx = xs; xx < xe; xx++)
            s += c2[((size_t)yy * CONVH + xx) * 64 + o];
    comb[(size_t)pix * 192 + 128 + o] = s / (float)((ye - ys) * (xe - xs));
}

// ---------------- dt = softplus(raw + bias), transposed out [h][t] ----------------
__global__ void dt_kernel(const float* __restrict__ zx, const float* __restrict__ dt_bias,
                          float* __restrict__ dtbT){
    int t = blockIdx.x * 256 + threadIdx.x;
    int h = blockIdx.y;
    if (t >= HW) return;
    float v = zx[(size_t)t * 772 + 768 + h] + dt_bias[h];
    dtbT[h * DTP + t] = (v > 20.f) ? v : log1pf(expf(v));
}

// ---------------- depthwise causal conv1d (width 4) + silu, LDS-tiled ----------------
__global__ __launch_bounds__(256) void conv1d_tiled(const float* __restrict__ zx,
                                                    const float* __restrict__ w,
                                                    const float* __restrict__ b,
                                                    float* __restrict__ xbc){
    __shared__ float xs[67 * 128];
    __shared__ float wc[4 * 128];
    __shared__ float bc[128];
    int t0 = blockIdx.y * 64;
    int c0 = blockIdx.x * 128;
    int tid = threadIdx.x;
    for (int e = tid; e < 67 * 128; e += 256){
        int rr = e >> 7, cc = e & 127;
        int t = t0 - 3 + rr;
        xs[e] = (t >= 0 && t < HW) ? zx[(size_t)t * 772 + 256 + c0 + cc] : 0.f;
    }
    if (tid < 128){
        bc[tid] = b[c0 + tid];
        #pragma unroll
        for (int k = 0; k < 4; k++) wc[k * 128 + tid] = w[(c0 + tid) * 4 + k];
    }
    __syncthreads();
    for (int e = tid; e < 64 * 128; e += 256){
        int tt = e >> 7, cc = e & 127;
        if (t0 + tt >= HW) continue;
        float acc = bc[cc];
        #pragma unroll
        for (int k = 0; k < 4; k++) acc += xs[(tt + k) * 128 + cc] * wc[k * 128 + cc];
        xbc[(size_t)(t0 + tt) * 512 + c0 + cc] = silu_f(acc);
    }
}

// ---------------- chunk cumsum (wave 0) ----------------
__device__ __forceinline__ void chunk_cumsum_t(const float* __restrict__ dtbT, int t0, int Q,
                                               int h, const float* __restrict__ A_log,
                                               float* cum, float* dth){
    int tid = threadIdx.x;
    if (tid < 64){
        float d = (tid < Q) ? dtbT[h * DTP + t0 + tid] : 0.f;
        dth[tid] = d;
        float A = -expf(A_log[h]);
        float a = d * A;
        #pragma unroll
        for (int off = 1; off < 64; off <<= 1){
            float u = __shfl_up(a, off);
            if (tid >= off) a += u;
        }
        cum[tid] = a;
    }
    __syncthreads();
}

// ---------------- SSD phase A (MFMA): S^T[p][n] = sum_s (X w)[s][p] B[s][n] ----------
__global__ __launch_bounds__(256) void ssd_phaseA(const float* __restrict__ xbc,
                                                  const float* __restrict__ dtbT,
                                                  const float* __restrict__ A_log,
                                                  float* __restrict__ S,
                                                  float* __restrict__ chunkT){
    __shared__ __align__(16) unsigned short BTh[128 * SP], BTl[128 * SP];
    __shared__ __align__(16) unsigned short XTh[64 * SP],  XTl[64 * SP];
    __shared__ float cum[64], dth[64], wln[64];
    int bid = blockIdx.x, c = bid >> 2, h = bid & 3;
    int t0 = c * QC, Q = min(QC, HW - t0);
    int tid = threadIdx.x;
    chunk_cumsum_t(dtbT, t0, Q, h, A_log, cum, dth);
    float T = cum[Q - 1];
    if (tid == 0) chunkT[bid] = T;
    if (tid < 64) wln[tid] = (tid < Q) ? __expf(T - cum[tid]) * dth[tid] : 0.f;
    __syncthreads();
    for (int e2 = tid; e2 < 4096; e2 += 256){
        int nn = e2 & 127, sp = e2 >> 7;
        int s0 = 2 * sp;
        float v0 = (s0 < Q)     ? xbc[(size_t)(t0 + s0) * 512 + 256 + nn] : 0.f;
        float v1 = (s0 + 1 < Q) ? xbc[(size_t)(t0 + s0 + 1) * 512 + 256 + nn] : 0.f;
        unsigned short h0, l0, h1, l1;
        bf16_split(v0, h0, l0); bf16_split(v1, h1, l1);
        *reinterpret_cast<unsigned*>(&BTh[nn * SP + s0]) = pack2(h0, h1);
        *reinterpret_cast<unsigned*>(&BTl[nn * SP + s0]) = pack2(l0, l1);
    }
    for (int e2 = tid; e2 < 2048; e2 += 256){
        int pp = e2 & 63, sp = e2 >> 6;
        int s0 = 2 * sp;
        float v0 = (s0 < Q)     ? xbc[(size_t)(t0 + s0) * 512 + h * 64 + pp] * wln[s0] : 0.f;
        float v1 = (s0 + 1 < Q) ? xbc[(size_t)(t0 + s0 + 1) * 512 + h * 64 + pp] * wln[s0 + 1] : 0.f;
        unsigned short h0, l0, h1, l1;
        bf16_split(v0, h0, l0); bf16_split(v1, h1, l1);
        *reinterpret_cast<unsigned*>(&XTh[pp * SP + s0]) = pack2(h0, h1);
        *reinterpret_cast<unsigned*>(&XTl[pp * SP + s0]) = pack2(l0, l1);
    }
    __syncthreads();
    int lane = tid & 63, wid = tid >> 6;
    int wy = wid >> 1, wx = wid & 1;
    int l15 = lane & 15, g = lane >> 4;
    fv4 acc[2][4];
    #pragma unroll
    for (int mi = 0; mi < 2; mi++)
        #pragma unroll
        for (int ni = 0; ni < 4; ni++) acc[mi][ni] = (fv4){0.f,0.f,0.f,0.f};
    #pragma unroll
    for (int ks = 0; ks < 2; ks++){
        short8 ah[2], al[2], bh_[4], bl_[4];
        #pragma unroll
        for (int mi = 0; mi < 2; mi++){
            unsigned off = (wy * 32 + mi * 16 + l15) * SP + ks * 32 + g * 8;
            ah[mi] = *reinterpret_cast<const short8*>(&XTh[off]);
            al[mi] = *reinterpret_cast<const short8*>(&XTl[off]);
        }
        #pragma unroll
        for (int ni = 0; ni < 4; ni++){
            unsigned off = (wx * 64 + ni * 16 + l15) * SP + ks * 32 + g * 8;
            bh_[ni] = *reinterpret_cast<const short8*>(&BTh[off]);
            bl_[ni] = *reinterpret_cast<const short8*>(&BTl[off]);
        }
        #pragma unroll
        for (int mi = 0; mi < 2; mi++)
            #pragma unroll
            for (int ni = 0; ni < 4; ni++){
                acc[mi][ni] = __builtin_amdgcn_mfma_f32_16x16x32_bf16(ah[mi], bh_[ni], acc[mi][ni], 0, 0, 0);
                acc[mi][ni] = __builtin_amdgcn_mfma_f32_16x16x32_bf16(ah[mi], bl_[ni], acc[mi][ni], 0, 0, 0);
                acc[mi][ni] = __builtin_amdgcn_mfma_f32_16x16x32_bf16(al[mi], bh_[ni], acc[mi][ni], 0, 0, 0);
            }
    }
    size_t sb = (size_t)bid * 8192;
    #pragma unroll
    for (int mi = 0; mi < 2; mi++)
        #pragma unroll
        for (int ni = 0; ni < 4; ni++)
            #pragma unroll
            for (int j = 0; j < 4; j++){
                int p = wy * 32 + mi * 16 + g * 4 + j;
                int n = wx * 64 + ni * 16 + l15;
                S[sb + p * 128 + n] = acc[mi][ni][j];
            }
}

// ---------------- SSD phase B: in-place prefix over chunks (pipelined) ------------
__global__ __launch_bounds__(256) void ssd_phaseB(float* __restrict__ S,
                                                  const float* __restrict__ chunkT){
    __shared__ float e[NCH];
    int tid = threadIdx.x;
    int idx = blockIdx.x * 256 + tid;
    int h = idx >> 13, pn = idx & 8191;
    for (int c = tid; c < NCH; c += 256) e[c] = __expf(chunkT[c * 4 + h]);
    __syncthreads();
    #define LDS_(cc) S[((size_t)((cc) * 4 + h)) * 8192 + pn]
    float b0 = LDS_(0), b1 = LDS_(1), b2 = LDS_(2), b3 = LDS_(3);
    float s = 0.f;
    int c = 0;
    for (; c + 8 <= NCH; c += 4){
        float n0 = LDS_(c + 4), n1 = LDS_(c + 5), n2 = LDS_(c + 6), n3 = LDS_(c + 7);
        LDS_(c) = s;     s = fmaf(s, e[c],     b0);
        LDS_(c + 1) = s; s = fmaf(s, e[c + 1], b1);
        LDS_(c + 2) = s; s = fmaf(s, e[c + 2], b2);
        LDS_(c + 3) = s; s = fmaf(s, e[c + 3], b3);
        b0 = n0; b1 = n1; b2 = n2; b3 = n3;
    }
    for (; c < NCH; c++){
        float nx = (c + 4 < NCH) ? LDS_(c + 4) : 0.f;
        float loc = b0; b0 = b1; b1 = b2; b2 = b3; b3 = nx;
        LDS_(c) = s;
        s = fmaf(s, e[c], loc);
    }
    #undef LDS_
}

// ---------------- SSD phase C (MFMA) ----------------
__global__ __launch_bounds__(256) void ssd_phaseC(const float* __restrict__ xbc,
                                                  const float* __restrict__ dtbT,
                                                  const float* __restrict__ A_log,
                                                  const float* __restrict__ Dvec,
                                                  const float* __restrict__ S,
                                                  float* __restrict__ y){
    __shared__ __align__(16) unsigned short Ch_[64 * SP], Cl_[64 * SP];
    __shared__ __align__(16) unsigned short Bh_[64 * SP], Bl_[64 * SP];
    __shared__ __align__(16) unsigned short Sh_[64 * SP], Sl_[64 * SP];
    __shared__ float cum[64], dth[64];
    int bid = blockIdx.x, c = bid >> 2, h = bid & 3;
    int t0 = c * QC, Q = min(QC, HW - t0);
    int tid = threadIdx.x;
    chunk_cumsum_t(dtbT, t0, Q, h, A_log, cum, dth);
    int lane = tid & 63, wid = tid >> 6;
    int wy = wid >> 1, wx = wid & 1;
    int l15 = lane & 15, g = lane >> 4;
    size_t sb = (size_t)bid * 8192;

    fv4 accG[2][2], accA[2][2];
    #pragma unroll
    for (int mi = 0; mi < 2; mi++)
        #pragma unroll
        for (int ni = 0; ni < 2; ni++){ accG[mi][ni] = (fv4){0.f,0.f,0.f,0.f}; accA[mi][ni] = (fv4){0.f,0.f,0.f,0.f}; }

    #pragma unroll
    for (int ks = 0; ks < 2; ks++){
        int n0 = ks * 64;
        for (int e2 = tid; e2 < 2048; e2 += 256){
            int rr = e2 >> 5, n2 = (e2 & 31) * 2;
            bool ok = rr < Q;
            float c0 = ok ? xbc[(size_t)(t0 + rr) * 512 + 384 + n0 + n2]     : 0.f;
            float c1 = ok ? xbc[(size_t)(t0 + rr) * 512 + 384 + n0 + n2 + 1] : 0.f;
            float b0 = ok ? xbc[(size_t)(t0 + rr) * 512 + 256 + n0 + n2]     : 0.f;
            float b1 = ok ? xbc[(size_t)(t0 + rr) * 512 + 256 + n0 + n2 + 1] : 0.f;
            float s0 = S[sb + rr * 128 + n0 + n2];
            float s1 = S[sb + rr * 128 + n0 + n2 + 1];
            unsigned short xh0, xl0, xh1, xl1;
            bf16_split(c0, xh0, xl0); bf16_split(c1, xh1, xl1);
            *reinterpret_cast<unsigned*>(&Ch_[rr * SP + n2]) = pack2(xh0, xh1);
            *reinterpret_cast<unsigned*>(&Cl_[rr * SP + n2]) = pack2(xl0, xl1);
            bf16_split(b0, xh0, xl0); bf16_split(b1, xh1, xl1);
            *reinterpret_cast<unsigned*>(&Bh_[rr * SP + n2]) = pack2(xh0, xh1);
            *reinterpret_cast<unsigned*>(&Bl_[rr * SP + n2]) = pack2(xl0, xl1);
            bf16_split(s0, xh0, xl0); bf16_split(s1, xh1, xl1);
            *reinterpret_cast<unsigned*>(&Sh_[rr * SP + n2]) = pack2(xh0, xh1);
            *reinterpret_cast<unsigned*>(&Sl_[rr * SP + n2]) = pack2(xl0, xl1);
        }
        __syncthreads();
        #pragma unroll
        for (int kk = 0; kk < 2; kk++){
            short8 ah[2], al[2], gh[2], gl[2], sh[2], sl[2];
            #pragma unroll
            for (int mi = 0; mi < 2; mi++){
                unsigned off = (wy * 32 + mi * 16 + l15) * SP + kk * 32 + g * 8;
                ah[mi] = *reinterpret_cast<const short8*>(&Ch_[off]);
                al[mi] = *reinterpret_cast<const short8*>(&Cl_[off]);
            }
            #pragma unroll
            for (int ni = 0; ni < 2; ni++){
                unsigned off = (wx * 32 + ni * 16 + l15) * SP + kk * 32 + g * 8;
                gh[ni] = *reinterpret_cast<const short8*>(&Bh_[off]);
                gl[ni] = *reinterpret_cast<const short8*>(&Bl_[off]);
                sh[ni] = *reinterpret_cast<const short8*>(&Sh_[off]);
                sl[ni] = *reinterpret_cast<const short8*>(&Sl_[off]);
            }
            #pragma unroll
            for (int mi = 0; mi < 2; mi++)
                #pragma unroll
                for (int ni = 0; ni < 2; ni++){
                    accG[mi][ni] = __builtin_amdgcn_mfma_f32_16x16x32_bf16(ah[mi], gh[ni], accG[mi][ni], 0, 0, 0);
                    accG[mi][ni] = __builtin_amdgcn_mfma_f32_16x16x32_bf16(ah[mi], gl[ni], accG[mi][ni], 0, 0, 0);
                    accG[mi][ni] = __builtin_amdgcn_mfma_f32_16x16x32_bf16(al[mi], gh[ni], accG[mi][ni], 0, 0, 0);
                    accA[mi][ni] = __builtin_amdgcn_mfma_f32_16x16x32_bf16(ah[mi], sh[ni], accA[mi][ni], 0, 0, 0);
                    accA[mi][ni] = __builtin_amdgcn_mfma_f32_16x16x32_bf16(ah[mi], sl[ni], accA[mi][ni], 0, 0, 0);
                    accA[mi][ni] = __builtin_amdgcn_mfma_f32_16x16x32_bf16(al[mi], sh[ni], accA[mi][ni], 0, 0, 0);
                }
        }
        __syncthreads();
    }
    #pragma unroll
    for (int mi = 0; mi < 2; mi++)
        #pragma unroll
        for (int ni = 0; ni < 2; ni++)
            #pragma unroll
            for (int j = 0; j < 4; j++){
                int t = wy * 32 + mi * 16 + g * 4 + j;
                int s = wx * 32 + ni * 16 + l15;
                float pv = 0.f;
                if (s <= t && s < Q)
                    pv = accG[mi][ni][j] * __expf(cum[t] - cum[s]) * dth[s];
                unsigned short hs, ls;
                bf16_split(pv, hs, ls);
                Bh_[t * SP + s] = hs;
                Bl_[t * SP + s] = ls;
            }
    for (int e2 = tid; e2 < 2048; e2 += 256){
        int pp = e2 & 63, sp = e2 >> 6;
        int s0 = 2 * sp;
        float v0 = (s0 < Q)     ? xbc[(size_t)(t0 + s0) * 512 + h * 64 + pp] : 0.f;
        float v1 = (s0 + 1 < Q) ? xbc[(size_t)(t0 + s0 + 1) * 512 + h * 64 + pp] : 0.f;
        unsigned short h0, l0, h1, l1;
        bf16_split(v0, h0, l0); bf16_split(v1, h1, l1);
        *reinterpret_cast<unsigned*>(&Ch_[pp * SP + s0]) = pack2(h0, h1);
        *reinterpret_cast<unsigned*>(&Cl_[pp * SP + s0]) = pack2(l0, l1);
    }
    __syncthreads();
    fv4 accY[2][2];
    #pragma unroll
    for (int mi = 0; mi < 2; mi++)
        #pragma unroll
        for (int ni = 0; ni < 2; ni++)
            #pragma unroll
            for (int j = 0; j < 4; j++){
                int t = wy * 32 + mi * 16 + g * 4 + j;
                accY[mi][ni][j] = __expf(cum[t]) * accA[mi][ni][j];
            }
    #pragma unroll
    for (int kk = 0; kk < 2; kk++){
        short8 ph[2], pl[2], xh[2], xl[2];
        #pragma unroll
        for (int mi = 0; mi < 2; mi++){
            unsigned off = (wy * 32 + mi * 16 + l15) * SP + kk * 32 + g * 8;
            ph[mi] = *reinterpret_cast<const short8*>(&Bh_[off]);
            pl[mi] = *reinterpret_cast<const short8*>(&Bl_[off]);
        }
        #pragma unroll
        for (int ni = 0; ni < 2; ni++){
            unsigned off = (wx * 32 + ni * 16 + l15) * SP + kk * 32 + g * 8;
            xh[ni] = *reinterpret_cast<const short8*>(&Ch_[off]);
            xl[ni] = *reinterpret_cast<const short8*>(&Cl_[off]);
        }
        #pragma unroll
        for (int mi = 0; mi < 2; mi++)
            #pragma unroll
            for (int ni = 0; ni < 2; ni++){
                accY[mi][ni] = __builtin_amdgcn_mfma_f32_16x16x32_bf16(ph[mi], xh[ni], accY[mi][ni], 0, 0, 0);
                accY[mi][ni] = __builtin_amdgcn_mfma_f32_16x16x32_bf16(ph[mi], xl[ni], accY[mi][ni], 0, 0, 0);
                accY[mi][ni] = __builtin_amdgcn_mfma_f32_16x16x32_bf16(pl[mi], xh[ni], accY[mi][ni], 0, 0, 0);
            }
    }
    float Dh = Dvec[h];
    #pragma unroll
    for (int mi = 0; mi < 2; mi++)
        #pragma unroll
        for (int ni = 0; ni < 2; ni++)
            #pragma unroll
            for (int j = 0; j < 4; j++){
                int t = wy * 32 + mi * 16 + g * 4 + j;
                if (t >= Q) continue;
                int p = wx * 32 + ni * 16 + l15;
                float xv = xbc[(size_t)(t0 + t) * 512 + h * 64 + p];
                y[(size_t)(t0 + t) * 256 + h * 64 + p] = accY[mi][ni][j] + Dh * xv;
            }
}

// ---------------- gated RMSNorm ----------------
__global__ void gated_rms_kernel(float* __restrict__ y, const float* __restrict__ zx,
                                 const float* __restrict__ nw){
    int row = blockIdx.x, tid = threadIdx.x;
    float v = y[(size_t)row * 256 + tid];
    float z = zx[(size_t)row * 772 + tid];
    v *= silu_f(z);
    float s = v * v;
    __shared__ float r1[4];
    #pragma unroll
    for (int o = 32; o > 0; o >>= 1) s += __shfl_down(s, o);
    if ((tid & 63) == 0) r1[tid >> 6] = s;
    __syncthreads();
    float S = r1[0] + r1[1] + r1[2] + r1[3];
    float rs = rsqrtf(S / 256.f + 1e-5f);
    y[(size_t)row * 256 + tid] = v * rs * nw[tid];
}

extern "C" void kernel_launch(void* const* d_in, const int* in_sizes, int n_in,
                              void* d_out, int out_size, void* d_ws, size_t ws_size,
                              hipStream_t stream){
    (void)in_sizes; (void)n_in; (void)out_size; (void)ws_size;
    const float* x        = (const float*)d_in[0];
    const float* ln_pre_g = (const float*)d_in[1];
    const float* ln_pre_b = (const float*)d_in[2];
    const float* fe_w1    = (const float*)d_in[3];
    const float* fe_b1    = (const float*)d_in[4];
    const float* fe_w2    = (const float*)d_in[5];
    const float* fe_b2    = (const float*)d_in[6];
    const float* cv_w1    = (const float*)d_in[7];
    const float* cv_b1    = (const float*)d_in[8];
    const float* cv_w2    = (const float*)d_in[9];
    const float* cv_b2    = (const float*)d_in[10];
    const float* mp_w     = (const float*)d_in[11];
    const float* mp_b     = (const float*)d_in[12];
    const float* mp_ln_g  = (const float*)d_in[13];
    const float* mp_ln_b  = (const float*)d_in[14];
    const float* m_in_w   = (const float*)d_in[15];
    const float* m_conv_w = (const float*)d_in[16];
    const float* m_conv_b = (const float*)d_in[17];
    const float* m_dtb    = (const float*)d_in[18];
    const float* m_A_log  = (const float*)d_in[19];
    const float* m_D      = (const float*)d_in[20];
    const float* m_norm_w = (const float*)d_in[21];
    const float* m_out_w  = (const float*)d_in[22];
    const float* cls_ln_g = (const float*)d_in[23];
    const float* cls_ln_b = (const float*)d_in[24];
    const float* cls_w1   = (const float*)d_in[25];
    const float* cls_b1   = (const float*)d_in[26];
    const float* cls_w2   = (const float*)d_in[27];
    const float* cls_b2   = (const float*)d_in[28];
    const float* cls_w3   = (const float*)d_in[29];
    const float* cls_b3   = (const float*)d_in[30];

    float* ws   = (float*)d_ws;
    float* xn   = ws + OFF_XN;
    float* f1   = ws + OFF_F1;
    float* comb = ws + OFF_COMB;
    float* p    = ws + OFF_P;
    float* zx   = ws + OFF_ZX;
    float* xbc  = ws + OFF_XBC;
    float* Sbuf = ws + OFF_S;
    float* dtbT = ws + OFF_DT;
    float* chkT = ws + OFF_CT;
    float* c1h  = ws + OFF_XBC;                    // before xbc live
    float* c2h  = ws + OFF_XBC + 691488;
    float* pr   = ws + OFF_XN;
    float* ybuf = ws + OFF_F1;
    float* mo   = ws + OFF_COMB;
    float* cls0 = ws + OFF_XN;
    float* cls1 = ws + OFF_P;
    float* cls2 = ws + OFF_COMB + 2691200;
    unsigned short* W1h = (unsigned short*)(ws + OFF_W);
    unsigned short* W1l = (unsigned short*)(ws + OFF_W + 32256);
    unsigned short* W2h = (unsigned short*)(ws + OFF_W + 64512);
    unsigned short* W2l = (unsigned short*)(ws + OFF_W + 73728);

    // 0. conv weight prepack (tiny)
    prep_w<200, 32, 7><<<(32 * 2016 + 255) / 256, 256, 0, stream>>>(cv_w1, W1h, W1l);
    prep_w<32, 64, 1><<<(64 * 288 + 255) / 256, 256, 0, stream>>>(cv_w2, W2h, W2l);
    // 1. pre-LN
    ln_kernel<0><<<HW, 256, 0, stream>>>(x, ln_pre_g, ln_pre_b, xn, NBANDS);
    // 2-3. feature MLP (f -> comb[:, :128], ldc=192)
    gemm_mfma<1><<<dim3(4, 165), 256, 0, stream>>>(xn, 200, fe_w1, fe_b1, f1, 256, HW, 256, 200);
    gemm_mfma<1><<<dim3(2, 165), 256, 0, stream>>>(f1, 256, fe_w2, fe_b2, comb, 192, HW, 128, 256);
    // 4. conv1 (MFMA implicit-im2col): 200->32, pad 2, in 145x145 -> out 147x147
    conv_mfma<200, 32, 2, 7, 1><<<dim3(3, CONVH), 256, 0, stream>>>(xn, Hdim, Wdim, W1h, W1l, cv_b1, c1h);
    // 5. conv2 (MFMA): 32->64, pad 1, in 147x147 -> out 147x147
    conv_mfma<32, 64, 1, 1, 2><<<dim3(3, CONVH), 256, 0, stream>>>(c1h, CONVH, CONVH, W2h, W2l, cv_b2, c2h);
    // 6. adaptive pool -> comb[:, 128:192]
    pool_kernel<<<(HW * 64 + 255) / 256, 256, 0, stream>>>(c2h, comb);
    // 7-8. mid projection + LN + GELU
    gemm_mfma<0><<<dim3(2, 165), 256, 0, stream>>>(comb, 192, mp_w, mp_b, pr, 128, HW, 128, 192);
    ln_kernel<1><<<HW, 256, 0, stream>>>(pr, mp_ln_g, mp_ln_b, p, 128);
    // 9. mamba in_proj
    gemm_mfma<0><<<dim3(13, 165), 256, 0, stream>>>(p, 128, m_in_w, (const float*)nullptr, zx, 772, HW, 772, 128);
    // 10. dt softplus (transposed [h][t])
    dt_kernel<<<dim3((HW + 255) / 256, 4), 256, 0, stream>>>(zx, m_dtb, dtbT);
    // 11. depthwise causal conv + silu (tiled)
    conv1d_tiled<<<dim3(4, NCH), 256, 0, stream>>>(zx, m_conv_w, m_conv_b, xbc);
    // 12-14. SSD chunked scan (MFMA)
    ssd_phaseA<<<NCH * 4, 256, 0, stream>>>(xbc, dtbT, m_A_log, Sbuf, chkT);
    ssd_phaseB<<<128, 256, 0, stream>>>(Sbuf, chkT);
    ssd_phaseC<<<NCH * 4, 256, 0, stream>>>(xbc, dtbT, m_A_log, m_D, Sbuf, ybuf);
    // 15. gated RMSNorm
    gated_rms_kernel<<<HW, 256, 0, stream>>>(ybuf, zx, m_norm_w);
    // 16. out proj
    gemm_mfma<0><<<dim3(2, 165), 256, 0, stream>>>(ybuf, 256, m_out_w, (const float*)nullptr, mo, 128, HW, 128, 256);
    // 17-20. classifier
    ln_kernel<0><<<HW, 256, 0, stream>>>(mo, cls_ln_g, cls_ln_b, cls0, 128);
    gemm_mfma<1><<<dim3(2, 165), 256, 0, stream>>>(cls0, 128, cls_w1, cls_b1, cls1, 128, HW, 128, 128);
    gemm_mfma<1><<<dim3(1, 165), 256, 0, stream>>>(cls1, 128, cls_w2, cls_b2, cls2, 64, HW, 64, 128);
    gemm_mfma<0><<<dim3(1, 165), 256, 0, stream>>>(cls2, 64, cls_w3, cls_b3, (float*)d_out, 17, HW, 17, 64);
}